// Round 7
// baseline (551.895 us; speedup 1.0000x reference)
//
#include <hip/hip_runtime.h>

#define NN 50000
#define NE 800000
#define DD 64
#define NL 5
#define NG 256
#define NC 10
#define BN_EPS 1e-5f
#define NCHUNK ((NN + 255) / 256)   // 196
#define GROWS 128                    // rows per gemm block (R4-proven)
#define GT (GROWS / 16)              // 16-row tiles per block
#define SAW 68                       // staged-A row stride (uints)
#define GEMM_BLOCKS ((NN + GROWS - 1) / GROWS)   // 391
#define NNS (NN + 8)                 // QVq per-quarter row stride (sentinel at row NN)
#define PADDEG(d) (((d) + 7) & ~7)   // csr segment padded to multiple of 8
#define DEG_BLOCKS ((NE + 255) / 256)        // 3125
#define WPREP_BLOCKS ((NL * 2048 + 255) / 256)  // 40
#define FCHK 2048                            // edges per fill chunk
#define FCHUNKS ((NE + FCHK - 1) / FCHK)     // 391
#define FILLP_BLOCKS (8 * FCHUNKS)           // 3128 (8 dst-ranges x chunks)
#define NRANGE (NN / 8)                      // 6250 nodes per dst-range
#define PAD_BLOCKS NCHUNK                    // 196
#define POOL_ROWS 64
#define POOL_BLOCKS ((NN + 8 * POOL_ROWS - 1) / (8 * POOL_ROWS))   // 98
#define L2E 1.4426950408889634f              // log2(e)

typedef __attribute__((ext_vector_type(8))) short bf16x8;
typedef __attribute__((ext_vector_type(4))) float f32x4;

__device__ inline float bf2f(unsigned short u) {
    return __uint_as_float((unsigned)u << 16);
}
__device__ inline unsigned short f2bf(float x) {   // RNE
    unsigned u = __float_as_uint(x);
    u += 0x7FFFu + ((u >> 16) & 1u);
    return (unsigned short)(u >> 16);
}

// Pack two floats as bf16 (RNE) into one uint: low16 = a, high16 = b.
__device__ inline unsigned int pack_bf16x2(float a, float b) {
    unsigned int ua = __float_as_uint(a);
    unsigned int ub = __float_as_uint(b);
    ua += 0x7FFFu + ((ua >> 16) & 1u);
    ub += 0x7FFFu + ((ub >> 16) & 1u);
    return (ub & 0xFFFF0000u) | (ua >> 16);
}

// Split fp32 into bf16 hi (RTZ) + bf16 lo (residual). hi+lo ~ x to ~2^-17.
__device__ inline void split_bf16(float x, short& h, short& l) {
    const unsigned u  = __float_as_uint(x);
    const unsigned hb = u & 0xFFFF0000u;
    h = (short)(hb >> 16);
    const float lo = x - __uint_as_float(hb);
    l = (short)(__float_as_uint(lo) >> 16);
}

// packed (e^-q | v) accessors: low16 = e^-q, high16 = v.
__device__ inline float p_eq(unsigned p) { return __uint_as_float(p << 16); }
__device__ inline float p_v(unsigned p)  { return __uint_as_float(p & 0xFFFF0000u); }

// Two gates sharing one ek (batched reciprocal, 1 rcp for 2 gates):
// v1/t1 + v2/t2 = (v1*t2 + v2*t1) * rcp(t1*t2).  [numerics proven in R2]
#define GPAIR(ek, pa, pb, acc) { \
    const float t1_ = fmaf(ek, p_eq(pa), 1.f); \
    const float t2_ = fmaf(ek, p_eq(pb), 1.f); \
    const float R_  = __builtin_amdgcn_rcpf(t1_ * t2_); \
    acc = fmaf(fmaf(p_v(pb), t1_, p_v(pa) * t2_), R_, acc); }

// Two gates with different ek (one uint2's two cols): inverse recovery,
// R=rcp(t1*t2); 1/t1=R*t2; 1/t2=R*t1.  [numerics proven in R2]
#define GCOLS(ekx, eky, p, accx, accy) { \
    const float t1_ = fmaf(ekx, p_eq(p.x), 1.f); \
    const float t2_ = fmaf(eky, p_eq(p.y), 1.f); \
    const float R_  = __builtin_amdgcn_rcpf(t1_ * t2_); \
    accx = fmaf(p_v(p.x), R_ * t2_, accx); \
    accy = fmaf(p_v(p.y), R_ * t1_, accy); }

// ---------------------------------------------------------------------------
// Shared GEMM body (MFMA, inline prev-layer BN for bf16 path, QUARTER-MAJOR
// outputs): Kq stores e^-k; QVq packs (e^-q | v); Hq stores skip+bias.
// exp via raw v_exp_f32: e^-(acc+b) = 2^fma(acc,-log2e, -b*log2e).
// F32=1: layer-0 path (fp32 X input, no BN fold).
// ---------------------------------------------------------------------------
template<int F32>
__device__ __forceinline__ void gemm_body(
    const void* __restrict__ HinV,
    const bf16x8* __restrict__ whbuf, const bf16x8* __restrict__ wlbuf,
    const float* __restrict__ bk, const float* __restrict__ bq,
    const float* __restrict__ bv, const float* __restrict__ bs,
    const float* __restrict__ prevStats,
    const float* __restrict__ prevGamma, const float* __restrict__ prevBeta,
    unsigned short* __restrict__ Kq, unsigned int* __restrict__ QVq,
    unsigned short* __restrict__ Hq, const int gb)
{
    __shared__ unsigned int sA[GROWS * SAW];   // packed split-bf16 A
    __shared__ float sAB[128];                 // a[64], b[64]
    const int tid = threadIdx.x;

    if (!F32) {
        if (tid < 64) {
            const float invN = 1.0f / (float)NN;
            const float mean = prevStats[tid] * invN;
            const float var  = prevStats[64 + tid] * invN - mean * mean;
            const float inv  = rsqrtf(var + BN_EPS);
            const float a = inv * prevGamma[tid];
            sAB[tid]      = a;
            sAB[64 + tid] = prevBeta[tid] - mean * a;
        }
        __syncthreads();
    }

    const int row0 = gb * GROWS;
    if (F32) {
        const float* X = (const float*)HinV;
        for (int i = tid; i < GROWS * 16; i += 256) {
            const int row = i >> 4;
            const int k4  = (i & 15) * 4;
            float4 x = make_float4(0.f, 0.f, 0.f, 0.f);
            if (row0 + row < NN)
                x = *(const float4*)(X + (size_t)(row0 + row) * DD + k4);
            const float xs[4] = {x.x, x.y, x.z, x.w};
            unsigned int* dst = &sA[row * SAW + k4];
#pragma unroll
            for (int j = 0; j < 4; j++) {
                short hs, ls;
                split_bf16(xs[j], hs, ls);
                dst[j] = ((unsigned int)(unsigned short)hs << 16) | (unsigned short)ls;
            }
        }
    } else {
        const unsigned short* Hin = (const unsigned short*)HinV;
        for (int i = tid; i < GROWS * 8; i += 256) {
            const int row = i >> 3;
            const int cb  = (i & 7) * 8;   // col base: 0,8,..,56
            const int q   = cb >> 4;
            const int o16 = cb & 15;       // 0 or 8
            uint4 v = make_uint4(0u, 0u, 0u, 0u);
            if (row0 + row < NN)
                v = *(const uint4*)&Hin[((size_t)q * NN + row0 + row) * 16 + o16];
            const unsigned ws[4] = {v.x, v.y, v.z, v.w};
            unsigned int* dst = &sA[row * SAW + cb];
#pragma unroll
            for (int j = 0; j < 4; j++) {
                const float x0 = bf2f((unsigned short)(ws[j] & 0xFFFFu));
                const float x1 = bf2f((unsigned short)(ws[j] >> 16));
                const int c0 = cb + 2 * j, c1 = cb + 2 * j + 1;
                short hs, ls;
                split_bf16(fmaf(x0, sAB[c0], sAB[64 + c0]), hs, ls);
                dst[2 * j] = ((unsigned int)(unsigned short)hs << 16) | (unsigned short)ls;
                split_bf16(fmaf(x1, sAB[c1], sAB[64 + c1]), hs, ls);
                dst[2 * j + 1] = ((unsigned int)(unsigned short)hs << 16) | (unsigned short)ls;
            }
        }
    }

    const int wave = tid >> 6;    // column tile == quarter
    const int lane = tid & 63;
    const int n15  = lane & 15;
    const int g    = lane >> 4;
    const int col  = wave * 16 + n15;

    bf16x8 wh[4][2], wl[4][2];
    {
        const int base = wave * 64 + lane;
#pragma unroll
        for (int m = 0; m < 4; m++)
#pragma unroll
            for (int c = 0; c < 2; c++) {
                const int idx = m * 512 + c * 256 + base;
                wh[m][c] = whbuf[idx];
                wl[m][c] = wlbuf[idx];
            }
    }

    const float nbk = -bk[col] * L2E;   // folded: 2^(acc*-L2E + nbk) = e^-(acc+bk)
    const float nbq = -bq[col] * L2E;
    const float bvc = bv[col], bsc = bs[col];
    __syncthreads();

#pragma unroll 1
    for (int t = 0; t < GT; t++) {
        const int rowbase = row0 + t * 16;
        if (rowbase >= NN) break;   // NN % 16 == 0

        bf16x8 ah[2], al[2];
#pragma unroll
        for (int c = 0; c < 2; c++) {
            const uint4 u0 = *(const uint4*)&sA[(t * 16 + n15) * SAW + g * 8 + 32 * c];
            const uint4 u1 = *(const uint4*)&sA[(t * 16 + n15) * SAW + g * 8 + 32 * c + 4];
            const unsigned int us[8] = {u0.x, u0.y, u0.z, u0.w, u1.x, u1.y, u1.z, u1.w};
            bf16x8 h, l;
#pragma unroll
            for (int j = 0; j < 8; j++) {
                h[j] = (short)(us[j] >> 16);
                l[j] = (short)(us[j] & 0xFFFFu);
            }
            ah[c] = h; al[c] = l;
        }

        f32x4 acc[4];
#pragma unroll
        for (int m = 0; m < 4; m++) acc[m] = (f32x4){0.f, 0.f, 0.f, 0.f};

#pragma unroll
        for (int c = 0; c < 2; c++) {
#pragma unroll
            for (int m = 0; m < 4; m++) {
                acc[m] = __builtin_amdgcn_mfma_f32_16x16x32_bf16(ah[c], wh[m][c], acc[m], 0, 0, 0);
                acc[m] = __builtin_amdgcn_mfma_f32_16x16x32_bf16(al[c], wh[m][c], acc[m], 0, 0, 0);
                acc[m] = __builtin_amdgcn_mfma_f32_16x16x32_bf16(ah[c], wl[m][c], acc[m], 0, 0, 0);
            }
        }

#pragma unroll
        for (int r = 0; r < 4; r++) {
            const int row = rowbase + g * 4 + r;
            const size_t o  = ((size_t)wave * NN  + row) * 16 + n15;
            const size_t oq = ((size_t)wave * NNS + row) * 16 + n15;
            Kq[o]   = f2bf(__builtin_amdgcn_exp2f(fmaf(acc[0][r], -L2E, nbk)));
            QVq[oq] = pack_bf16x2(__builtin_amdgcn_exp2f(fmaf(acc[1][r], -L2E, nbq)),
                                  acc[2][r] + bvc);
            Hq[o]   = f2bf(acc[3][r] + bsc);
        }
    }
}

// ---------------------------------------------------------------------------
// Fused prep: deg histogram (blocks 0..3124) + W-fragment split (blocks
// 3125..3164) + QVq sentinel-row zeroing. Independent work, one launch.
// ---------------------------------------------------------------------------
__global__ __launch_bounds__(256) void prep_kernel(
    const int* __restrict__ ei, int* __restrict__ deg,
    const float* __restrict__ Wk, const float* __restrict__ Wq,
    const float* __restrict__ Wv, const float* __restrict__ Ws,
    bf16x8* __restrict__ whbuf, bf16x8* __restrict__ wlbuf,
    unsigned int* __restrict__ QVq)
{
    const int bid = blockIdx.x;
    if (bid < DEG_BLOCKS) {
        const int e = bid * 256 + threadIdx.x;
        if (e < NE) atomicAdd(&deg[ei[NE + e]], 1);
        return;
    }
    if (bid == DEG_BLOCKS && threadIdx.x < 64) {
        const int q = threadIdx.x >> 4, c = threadIdx.x & 15;
        QVq[((size_t)q * NNS + NN) * 16 + c] = 0u;   // sentinel row: e^-q=0, v=0
    }
    const int t = (bid - DEG_BLOCKS) * 256 + threadIdx.x;
    if (t >= NL * 2048) return;
    const int lane = t & 63;
    const int w    = (t >> 6) & 3;
    const int c    = (t >> 8) & 1;
    const int m    = (t >> 9) & 3;
    const int l    = t >> 11;

    const float* Wm4[4] = {Wk, Wq, Wv, Ws};
    const float* W = Wm4[m] + l * 4096;
    const int col = w * 16 + (lane & 15);
    const int g   = lane >> 4;

    bf16x8 h, lo;
#pragma unroll
    for (int j = 0; j < 8; j++) {
        const int k = g * 8 + j + 32 * c;
        short hs, ls;
        split_bf16(W[k * DD + col], hs, ls);
        h[j] = hs; lo[j] = ls;
    }
    whbuf[t] = h;
    wlbuf[t] = lo;
}

// ---------------------------------------------------------------------------
// Scan over PADDED degrees, stage 1 + FUSED stage 2 (last-block ticket):
// each block publishes its padded-degree sum via atomicExch; the last block
// to arrive runs the 64-lane wave scan in-place (atomic reads — no reliance
// on cross-XCD L2 coherence) and writes rowst[NN]. Saves one launch + gap.
// ---------------------------------------------------------------------------
__global__ __launch_bounds__(256) void scan_partial_kernel(
    const int* __restrict__ deg, int* __restrict__ psums,
    int* __restrict__ rowst, int* __restrict__ ticket)
{
    __shared__ int ls[256];
    __shared__ int amLast;
    const int i = blockIdx.x * 256 + threadIdx.x;
    ls[threadIdx.x] = (i < NN) ? PADDEG(deg[i]) : 0;
    __syncthreads();
    for (int off = 128; off > 0; off >>= 1) {
        if (threadIdx.x < off) ls[threadIdx.x] += ls[threadIdx.x + off];
        __syncthreads();
    }
    if (threadIdx.x == 0) {
        atomicExch(&psums[blockIdx.x], ls[0]);   // device-scope publish
        __threadfence();
        amLast = (atomicAdd(ticket, 1) == NCHUNK - 1);
    }
    __syncthreads();
    if (!amLast || threadIdx.x >= 64) return;

    // last block: wave-parallel exclusive scan over NCHUNK partials
    const int lane = threadIdx.x;
    const int base = lane * 4;
    int v[4];
    int s = 0;
#pragma unroll
    for (int j = 0; j < 4; j++) {
        v[j] = (base + j < NCHUNK) ? atomicAdd(&psums[base + j], 0) : 0;
        s += v[j];
    }
    int incl = s;
    for (int off = 1; off < 64; off <<= 1) {
        const int t = __shfl_up(incl, off);
        if (lane >= off) incl += t;
    }
    const int total = __shfl(incl, 63);
    int run = incl - s;   // exclusive
#pragma unroll
    for (int j = 0; j < 4; j++) {           // consumed next launch (boundary-coherent)
        if (base + j < NCHUNK) psums[base + j] = run;
        run += v[j];
    }
    if (lane == 0) rowst[NN] = total;  // padded edge total
}

__global__ __launch_bounds__(256) void scan_final_kernel(
    const int* __restrict__ deg, const int* __restrict__ psums,
    int* __restrict__ rowst, int* __restrict__ cursor)
{
    __shared__ int ls[256];
    const int i = blockIdx.x * 256 + threadIdx.x;
    const int x = (i < NN) ? PADDEG(deg[i]) : 0;
    ls[threadIdx.x] = x;
    __syncthreads();
    for (int off = 1; off < 256; off <<= 1) {
        int v = (threadIdx.x >= off) ? ls[threadIdx.x - off] : 0;
        __syncthreads();
        ls[threadIdx.x] += v;
        __syncthreads();
    }
    if (i < NN) {
        const int excl = psums[blockIdx.x] + ls[threadIdx.x] - x;
        rowst[i]  = excl;
        cursor[i] = excl;
    }
}

// ---------------------------------------------------------------------------
// Fused gemm0 + RANGE-PARTITIONED CSR fill + sentinel pad (R4-proven).
// ---------------------------------------------------------------------------
__global__ __launch_bounds__(256) void gfp_kernel(
    const float* __restrict__ X,
    const bf16x8* __restrict__ whbuf, const bf16x8* __restrict__ wlbuf,
    const float* __restrict__ bk, const float* __restrict__ bq,
    const float* __restrict__ bv, const float* __restrict__ bs,
    unsigned short* __restrict__ Kq, unsigned int* __restrict__ QVq,
    unsigned short* __restrict__ Hq,
    const int* __restrict__ ei, int* __restrict__ cursor,
    const int* __restrict__ rowst, const int* __restrict__ deg,
    unsigned short* __restrict__ csr16)
{
    const int bid = blockIdx.x;
    if (bid < GEMM_BLOCKS) {
        gemm_body<1>(X, whbuf, wlbuf, bk, bq, bv, bs,
                     nullptr, nullptr, nullptr, Kq, QVq, Hq, bid);
        return;
    }
    if (bid < GEMM_BLOCKS + FILLP_BLOCKS) {
        const int fid = bid - GEMM_BLOCKS;
        const int r   = bid & 7;            // dst-range == XCD (heuristic)
        const int o   = fid >> 3;           // edge chunk ordinal
        const int lo  = r * NRANGE;
        const int hi  = lo + NRANGE;
        const int e0  = o * FCHK;
        const int e1  = min(e0 + FCHK, NE);
        for (int e = e0 + threadIdx.x; e < e1; e += 256) {
            const int dst = ei[NE + e];
            if (dst >= lo && dst < hi) {
                const int src = ei[e];      // < 50000 < 65536 -> u16 exact
                csr16[atomicAdd(&cursor[dst], 1)] = (unsigned short)src;
            }
        }
        return;
    }
    const int n = (bid - GEMM_BLOCKS - FILLP_BLOCKS) * 256 + threadIdx.x;
    if (n >= NN) return;
    const int end = rowst[n + 1];
    for (int i = rowst[n] + deg[n]; i < end; i++) csr16[i] = (unsigned short)NN;
}

// ---------------------------------------------------------------------------
// gemm for layers 1..4 (bf16 input, prev-layer BN folded).
// ---------------------------------------------------------------------------
__global__ __launch_bounds__(256) void gemm4_mfma(
    const void* __restrict__ HinV,
    const bf16x8* __restrict__ whbuf, const bf16x8* __restrict__ wlbuf,
    const float* __restrict__ bk, const float* __restrict__ bq,
    const float* __restrict__ bv, const float* __restrict__ bs,
    const float* __restrict__ prevStats,
    const float* __restrict__ prevGamma, const float* __restrict__ prevBeta,
    unsigned short* __restrict__ Kq, unsigned int* __restrict__ QVq,
    unsigned short* __restrict__ Hq)
{
    gemm_body<0>(HinV, whbuf, wlbuf, bk, bq, bv, bs,
                 prevStats, prevGamma, prevBeta, Kq, QVq, Hq, blockIdx.x);
}

// ---------------------------------------------------------------------------
// Column-quarter XCD-partitioned gather — EXACT R4 version (best measured,
// 55.1 us): u32 csr + GPAIR batched rcp, GCOLS tails, rowst carry, masked
// Hq prefetch. R5 (readfirstlane) and R6 (csr prefetch) both regressed and
// are reverted; scheduling/ILP grafts on this kernel consistently lose to
// the compiler's schedule — only work removal has ever helped it.
// ---------------------------------------------------------------------------
#define GATHER_BLOCKS (8 * 782)   // 6256
__global__ __launch_bounds__(256) void gather_kernel(
    const int* __restrict__ rowst, const unsigned short* __restrict__ csr16,
    const unsigned short* __restrict__ Kq, const unsigned int* __restrict__ QVq,
    unsigned short* Hq, float* __restrict__ stats)
{
    const int tid  = threadIdx.x;
    const int wv   = tid >> 6;
    const int lane = tid & 63;
    const int eoff = lane >> 3;     // edge slot 0..7
    const int cp   = lane & 7;      // column pair (cols 2cp, 2cp+1)

    const int j       = blockIdx.x;
    const int xcd     = j & 7;
    const int quarter = xcd >> 1;
    const int half    = xcd & 1;
    const int nodebase = ((j >> 3) * 2 + half) * 32 + wv * 8;

    const unsigned* Kq32 = (const unsigned*)(Kq + (size_t)quarter * NN * 16);
    const uint2*    Qq2  = (const uint2*)(QVq + (size_t)quarter * NNS * 16);
    unsigned*       Hq32 = (unsigned*)(Hq + (size_t)quarter * NN * 16);

    float se = 0.f, s2e = 0.f, so = 0.f, s2o = 0.f;   // stats cols 2cp / 2cp+1

    int e00 = rowst[min(nodebase, NN)];   // carried: e00(t+1) = e11(t)

    for (int t = 0; t < 4; t++) {
        const int n0 = nodebase + 2 * t;   // even; n1 = n0+1 < NN when n0 < NN
        if (n0 >= NN) break;
        const int n1 = n0 + 1;
        const unsigned ho0 = (unsigned)(n0 * 8 + cp);
        const unsigned ho1 = (unsigned)(n1 * 8 + cp);
        unsigned h0p = 0u, h1p = 0u;
        if (eoff == 0) {                   // exec-masked prefetch of skip term
            h0p = Hq32[ho0];
            h1p = Hq32[ho1];
        }
        const unsigned k0p = Kq32[ho0];    // packed e^-k
        const unsigned k1p = Kq32[ho1];
        const float ek00 = bf2f((unsigned short)(k0p & 0xFFFFu));
        const float ek01 = bf2f((unsigned short)(k0p >> 16));
        const float ek10 = bf2f((unsigned short)(k1p & 0xFFFFu));
        const float ek11 = bf2f((unsigned short)(k1p >> 16));
        const int e01 = rowst[n1], e11 = rowst[n1 + 1];
        int nd0 = (e01 - e00) >> 3;        // padded slot counts
        int nd1 = (e11 - e01) >> 3;
        int ndm = min(nd0, nd1);
        nd0 -= ndm; nd1 -= ndm;
        int b0 = e00, b1 = e01;            // base edge indices (even)
        e00 = e11;                         // carry for next t
        float a00 = 0.f, a01 = 0.f, a10 = 0.f, a11 = 0.f;

        // dual-node main loop: 16 edges/node per iter, 2 u32 csr + 4 uint2
        // QVq loads in flight, 4 rcp per 8 gates.
        while (ndm >= 2) {
            const unsigned s0 = *(const unsigned*)(csr16 + b0 + 2 * eoff);
            const unsigned s1 = *(const unsigned*)(csr16 + b1 + 2 * eoff);
            const uint2 p0a = Qq2[(s0 & 0xFFFFu) * 8u + cp];
            const uint2 p0b = Qq2[(s0 >> 16) * 8u + cp];
            const uint2 p1a = Qq2[(s1 & 0xFFFFu) * 8u + cp];
            const uint2 p1b = Qq2[(s1 >> 16) * 8u + cp];
            GPAIR(ek00, p0a.x, p0b.x, a00);
            GPAIR(ek01, p0a.y, p0b.y, a01);
            GPAIR(ek10, p1a.x, p1b.x, a10);
            GPAIR(ek11, p1a.y, p1b.y, a11);
            b0 += 16; b1 += 16; ndm -= 2;
        }
        if (ndm) {   // one joint slot left (u16 per lane)
            const int s0 = csr16[b0 + eoff];
            const int s1 = csr16[b1 + eoff];
            const uint2 p0 = Qq2[(unsigned)(s0 * 8 + cp)];
            const uint2 p1 = Qq2[(unsigned)(s1 * 8 + cp)];
            GCOLS(ek00, ek01, p0, a00, a01);
            GCOLS(ek10, ek11, p1, a10, a11);
            b0 += 8; b1 += 8;
        }
        while (nd0 >= 2) {   // node-0 surplus, 16-edge steps
            const unsigned s0 = *(const unsigned*)(csr16 + b0 + 2 * eoff);
            const uint2 p0a = Qq2[(s0 & 0xFFFFu) * 8u + cp];
            const uint2 p0b = Qq2[(s0 >> 16) * 8u + cp];
            GPAIR(ek00, p0a.x, p0b.x, a00);
            GPAIR(ek01, p0a.y, p0b.y, a01);
            b0 += 16; nd0 -= 2;
        }
        if (nd0) {
            const int s0 = csr16[b0 + eoff];
            const uint2 p0 = Qq2[(unsigned)(s0 * 8 + cp)];
            GCOLS(ek00, ek01, p0, a00, a01);
        }
        while (nd1 >= 2) {   // node-1 surplus, 16-edge steps
            const unsigned s1 = *(const unsigned*)(csr16 + b1 + 2 * eoff);
            const uint2 p1a = Qq2[(s1 & 0xFFFFu) * 8u + cp];
            const uint2 p1b = Qq2[(s1 >> 16) * 8u + cp];
            GPAIR(ek10, p1a.x, p1b.x, a10);
            GPAIR(ek11, p1a.y, p1b.y, a11);
            b1 += 16; nd1 -= 2;
        }
        if (nd1) {
            const int s1 = csr16[b1 + eoff];
            const uint2 p1 = Qq2[(unsigned)(s1 * 8 + cp)];
            GCOLS(ek10, ek11, p1, a10, a11);
        }

        // combine edge slots: lanes cp, cp+8, ..., cp+56 share columns
        a00 += __shfl_xor(a00, 8);  a00 += __shfl_xor(a00, 16); a00 += __shfl_xor(a00, 32);
        a01 += __shfl_xor(a01, 8);  a01 += __shfl_xor(a01, 16); a01 += __shfl_xor(a01, 32);
        a10 += __shfl_xor(a10, 8);  a10 += __shfl_xor(a10, 16); a10 += __shfl_xor(a10, 32);
        a11 += __shfl_xor(a11, 8);  a11 += __shfl_xor(a11, 16); a11 += __shfl_xor(a11, 32);

        if (eoff == 0) {
            const float o00 = fmaxf(bf2f((unsigned short)(h0p & 0xFFFFu)) + a00, 0.f);
            const float o01 = fmaxf(bf2f((unsigned short)(h0p >> 16))     + a01, 0.f);
            const float o10 = fmaxf(bf2f((unsigned short)(h1p & 0xFFFFu)) + a10, 0.f);
            const float o11 = fmaxf(bf2f((unsigned short)(h1p >> 16))     + a11, 0.f);
            const unsigned short b00 = f2bf(o00), b01 = f2bf(o01);
            const unsigned short b10 = f2bf(o10), b11 = f2bf(o11);
            Hq32[ho0] = ((unsigned)b01 << 16) | b00;
            Hq32[ho1] = ((unsigned)b11 << 16) | b10;
            const float r00 = bf2f(b00), r01 = bf2f(b01);
            const float r10 = bf2f(b10), r11 = bf2f(b11);
            se  += r00 + r10;  s2e += r00 * r00 + r10 * r10;
            so  += r01 + r11;  s2o += r01 * r01 + r11 * r11;
        }
    }

    __shared__ float ls[64], ls2[64];   // 4 waves x 16 cols
    if (eoff == 0) {
        ls[wv * 16 + 2 * cp]      = se;  ls2[wv * 16 + 2 * cp]      = s2e;
        ls[wv * 16 + 2 * cp + 1]  = so;  ls2[wv * 16 + 2 * cp + 1]  = s2o;
    }
    __syncthreads();
    if (tid < 16) {
        const float a = ls[tid] + ls[16 + tid] + ls[32 + tid] + ls[48 + tid];
        const float b = ls2[tid] + ls2[16 + tid] + ls2[32 + tid] + ls2[48 + tid];
        atomicAdd(&stats[quarter * 16 + tid], a);
        atomicAdd(&stats[64 + quarter * 16 + tid], b);
    }
}

// ---------------------------------------------------------------------------
// Pooled segment-sum over quarter-major bf16 H (batch sorted) + FUSED final
// head (last-block ticket): the last pool block to finish runs the
// mean -> BN-fold -> logits -> softmax for all 256 graphs, reading
// psum/pcnt via device atomics (they are atomic-written by pool blocks;
// stats comes from the prior gather launch so plain loads are safe).
// ---------------------------------------------------------------------------
__global__ __launch_bounds__(256) void pool_kernel(
    const unsigned short* __restrict__ Hq, const int* __restrict__ batch,
    float* __restrict__ psum, float* __restrict__ pcnt, int* __restrict__ ticket,
    const float* __restrict__ stats,
    const float* __restrict__ gamma, const float* __restrict__ beta,
    const float* __restrict__ Wlin, const float* __restrict__ blin,
    float* __restrict__ out)
{
    const int sub = threadIdx.x >> 5;   // chunk 0..7
    const int c   = threadIdx.x & 31;   // col-pair id
    const int q   = c >> 3;             // quarter
    const int p   = c & 7;              // pair within quarter (cols 2p, 2p+1)
    const int r0 = (blockIdx.x * 8 + sub) * POOL_ROWS;
    if (r0 < NN) {
        const int r1 = min(r0 + POOL_ROWS, NN);
        const unsigned* Hqq = (const unsigned*)(Hq + (size_t)q * NN * 16);
        const int col0 = q * 16 + 2 * p;

        int cur = batch[r0];
        float acc0 = 0.f, acc1 = 0.f, cnt = 0.f;
        for (int r = r0; r < r1; r++) {
            const int g = batch[r];
            if (g != cur) {
                atomicAdd(&psum[cur * DD + col0], acc0);
                atomicAdd(&psum[cur * DD + col0 + 1], acc1);
                if (c == 0) atomicAdd(&pcnt[cur], cnt);
                acc0 = 0.f; acc1 = 0.f; cnt = 0.f; cur = g;
            }
            const unsigned hv = Hqq[(size_t)r * 8 + p];
            acc0 += bf2f((unsigned short)(hv & 0xFFFFu));
            acc1 += bf2f((unsigned short)(hv >> 16));
            cnt += 1.f;
        }
        atomicAdd(&psum[cur * DD + col0], acc0);
        atomicAdd(&psum[cur * DD + col0 + 1], acc1);
        if (c == 0) atomicAdd(&pcnt[cur], cnt);
    }

    __shared__ int amLast;
    __syncthreads();
    if (threadIdx.x == 0) {
        __threadfence();
        amLast = (atomicAdd(ticket, 1) == POOL_BLOCKS - 1);
    }
    __syncthreads();
    if (!amLast) return;

    // ---- final head: one thread per graph ----
    const int g = threadIdx.x;   // NG == 256 == blockDim
    const float invc = 1.0f / fmaxf(atomicAdd(&pcnt[g], 0.f), 1.0f);
    const float invN = 1.0f / (float)NN;
    float pv[DD];
#pragma unroll
    for (int d = 0; d < DD; d++) {
        const float mean = stats[d] * invN;
        const float var  = stats[64 + d] * invN - mean * mean;
        const float inv  = rsqrtf(var + BN_EPS);
        const float a = inv * gamma[d];
        const float b = beta[d] - mean * a;
        pv[d] = fmaf(atomicAdd(&psum[g * DD + d], 0.f) * invc, a, b);
    }

    float logits[NC];
    float m = -1e30f;
#pragma unroll
    for (int cc = 0; cc < NC; cc++) {
        float acc = blin[cc];
#pragma unroll
        for (int d = 0; d < DD; d++) acc = fmaf(pv[d], Wlin[d * NC + cc], acc);
        logits[cc] = acc;
        m = fmaxf(m, acc);
    }
    float sum = 0.f;
#pragma unroll
    for (int cc = 0; cc < NC; cc++) {
        logits[cc] = __expf(logits[cc] - m);
        sum += logits[cc];
    }
    const float inv = 1.f / sum;
#pragma unroll
    for (int cc = 0; cc < NC; cc++) out[g * NC + cc] = logits[cc] * inv;
}

// ---------------------------------------------------------------------------
extern "C" void kernel_launch(void* const* d_in, const int* in_sizes, int n_in,
                              void* d_out, int out_size, void* d_ws, size_t ws_size,
                              hipStream_t stream)
{
    const float* X     = (const float*)d_in[0];
    const int*   ei    = (const int*)d_in[1];
    const int*   batch = (const int*)d_in[2];
    const float* Wk    = (const float*)d_in[3];
    const float* Wq    = (const float*)d_in[4];
    const float* Wv    = (const float*)d_in[5];
    const float* Ws    = (const float*)d_in[6];
    const float* bk    = (const float*)d_in[7];
    const float* bq    = (const float*)d_in[8];
    const float* bv    = (const float*)d_in[9];
    const float* bconv = (const float*)d_in[10];
    const float* gamma = (const float*)d_in[11];
    const float* beta  = (const float*)d_in[12];
    const float* Wlin  = (const float*)d_in[13];
    const float* blin  = (const float*)d_in[14];
    float* out = (float*)d_out;

    const size_t M  = (size_t)NN * DD;        // == 4 * NN * 16
    const size_t MQ = (size_t)4 * NNS * 16;   // QVq uints (padded stride)
    unsigned short* Kq  = (unsigned short*)d_ws;      // M bf16 (e^-k), quarter-major
    unsigned int*   QVq = (unsigned int*)(Kq + M);    // MQ packed (e^-q|v), stride NNS
    unsigned short* H0q = (unsigned short*)(QVq + MQ);// M bf16, quarter-major
    unsigned short* H1q = H0q + M;                    // M bf16
    // --- contiguous zero-init region ---
    int*   deg    = (int*)(H1q + M);                  // NN
    float* psum   = (float*)(deg + NN);               // NG*DD
    float* pcnt   = psum + (size_t)NG * DD;           // NG
    float* stats  = pcnt + NG;                        // NL*128
    int*   ticket = (int*)(stats + NL * 128);         // 2 (scan, pool)
    // --- end zero region ---
    int* rowst  = ticket + 2;                         // NN+1
    int* cursor = rowst + NN + 1;                     // NN
    int* psums  = cursor + NN;                        // 256
    unsigned short* csr16 = (unsigned short*)(psums + 256);  // NE + 8*NN u16 (padded)
    bf16x8* whbuf = (bf16x8*)(csr16 + NE + 8 * NN);   // NL*2048 frags
    bf16x8* wlbuf = whbuf + NL * 2048;

    const size_t zero_bytes = (size_t)(NN + NG * DD + NG + NL * 128 + 2) * 4;
    hipMemsetAsync(deg, 0, zero_bytes, stream);

    // ---- fused deg histogram + W fragment prep + sentinel zeroing ----
    prep_kernel<<<DEG_BLOCKS + WPREP_BLOCKS, 256, 0, stream>>>(
        ei, deg, Wk, Wq, Wv, Ws, whbuf, wlbuf, QVq);

    // ---- scans over padded degrees (stage 2 fused via last-block ticket) ----
    scan_partial_kernel<<<NCHUNK, 256, 0, stream>>>(deg, psums, rowst, ticket);
    scan_final_kernel<<<NCHUNK, 256, 0, stream>>>(deg, psums, rowst, cursor);

    // ---- fused layer-0 gemm + range-partitioned CSR fill + sentinel pad ----
    gfp_kernel<<<GEMM_BLOCKS + FILLP_BLOCKS + PAD_BLOCKS, 256, 0, stream>>>(
        X, whbuf, wlbuf, bk, bq, bv, bconv,
        Kq, QVq, H0q, ei, cursor, rowst, deg, csr16);

    // ---- layers ----
    gather_kernel<<<GATHER_BLOCKS, 256, 0, stream>>>(
        rowst, csr16, Kq, QVq, H0q, stats);
    const void* hin = (const void*)H0q;
    for (int l = 1; l < NL; l++) {
        unsigned short* hout = (l & 1) ? H1q : H0q;
        gemm4_mfma<<<GEMM_BLOCKS, 256, 0, stream>>>(
            hin, whbuf + l * 2048, wlbuf + l * 2048,
            bk + l * 64, bq + l * 64, bv + l * 64, bconv + l * 64,
            stats + (l - 1) * 128, gamma + (l - 1) * 64, beta + (l - 1) * 64,
            Kq, QVq, hout);
        gather_kernel<<<GATHER_BLOCKS, 256, 0, stream>>>(
            rowst, csr16, Kq, QVq, hout, stats + l * 128);
        hin = (const void*)hout;
    }

    // ---- pool + fused final head ----
    pool_kernel<<<POOL_BLOCKS, 256, 0, stream>>>(
        (const unsigned short*)hin, batch, psum, pcnt, ticket + 1,
        stats + 4 * 128, gamma + 4 * 64, beta + 4 * 64, Wlin, blin, out);
}

// Round 8
// 518.529 us; speedup vs baseline: 1.0643x; 1.0643x over previous
//
#include <hip/hip_runtime.h>

#define NN 50000
#define NE 800000
#define DD 64
#define NL 5
#define NG 256
#define NC 10
#define BN_EPS 1e-5f
#define NCHUNK ((NN + 255) / 256)   // 196
#define GROWS 128                    // rows per gemm block (R4-proven)
#define GT (GROWS / 16)              // 16-row tiles per block
#define SAW 68                       // staged-A row stride (uints)
#define GEMM_BLOCKS ((NN + GROWS - 1) / GROWS)   // 391
#define NNS (NN + 8)                 // QVq per-quarter row stride (sentinel at row NN)
#define PADDEG(d) (((d) + 7) & ~7)   // csr segment padded to multiple of 8
#define DEG_BLOCKS ((NE + 255) / 256)        // 3125
#define WPREP_BLOCKS ((NL * 2048 + 255) / 256)  // 40
#define FCHK 2048                            // edges per fill chunk
#define FCHUNKS ((NE + FCHK - 1) / FCHK)     // 391
#define FILLP_BLOCKS (8 * FCHUNKS)           // 3128 (8 dst-ranges x chunks)
#define NRANGE (NN / 8)                      // 6250 nodes per dst-range
#define PAD_BLOCKS NCHUNK                    // 196
#define SREP 4                               // stats replicas (atomic contention /4)
#define SSTR (SREP * 128)                    // per-layer stats stride (512 floats)
#define L2E 1.4426950408889634f              // log2(e)

typedef __attribute__((ext_vector_type(8))) short bf16x8;
typedef __attribute__((ext_vector_type(4))) float f32x4;

__device__ inline float bf2f(unsigned short u) {
    return __uint_as_float((unsigned)u << 16);
}
__device__ inline unsigned short f2bf(float x) {   // RNE
    unsigned u = __float_as_uint(x);
    u += 0x7FFFu + ((u >> 16) & 1u);
    return (unsigned short)(u >> 16);
}

// Pack two floats as bf16 (RNE) into one uint: low16 = a, high16 = b.
__device__ inline unsigned int pack_bf16x2(float a, float b) {
    unsigned int ua = __float_as_uint(a);
    unsigned int ub = __float_as_uint(b);
    ua += 0x7FFFu + ((ua >> 16) & 1u);
    ub += 0x7FFFu + ((ub >> 16) & 1u);
    return (ub & 0xFFFF0000u) | (ua >> 16);
}

// Split fp32 into bf16 hi (RTZ) + bf16 lo (residual). hi+lo ~ x to ~2^-17.
__device__ inline void split_bf16(float x, short& h, short& l) {
    const unsigned u  = __float_as_uint(x);
    const unsigned hb = u & 0xFFFF0000u;
    h = (short)(hb >> 16);
    const float lo = x - __uint_as_float(hb);
    l = (short)(__float_as_uint(lo) >> 16);
}

// packed (e^-q | v) accessors: low16 = e^-q, high16 = v.
__device__ inline float p_eq(unsigned p) { return __uint_as_float(p << 16); }
__device__ inline float p_v(unsigned p)  { return __uint_as_float(p & 0xFFFF0000u); }

// Two gates sharing one ek (batched reciprocal, 1 rcp for 2 gates):
// v1/t1 + v2/t2 = (v1*t2 + v2*t1) * rcp(t1*t2).  [numerics proven in R2]
#define GPAIR(ek, pa, pb, acc) { \
    const float t1_ = fmaf(ek, p_eq(pa), 1.f); \
    const float t2_ = fmaf(ek, p_eq(pb), 1.f); \
    const float R_  = __builtin_amdgcn_rcpf(t1_ * t2_); \
    acc = fmaf(fmaf(p_v(pb), t1_, p_v(pa) * t2_), R_, acc); }

// Two gates with different ek (one uint2's two cols): inverse recovery,
// R=rcp(t1*t2); 1/t1=R*t2; 1/t2=R*t1.  [numerics proven in R2]
#define GCOLS(ekx, eky, p, accx, accy) { \
    const float t1_ = fmaf(ekx, p_eq(p.x), 1.f); \
    const float t2_ = fmaf(eky, p_eq(p.y), 1.f); \
    const float R_  = __builtin_amdgcn_rcpf(t1_ * t2_); \
    accx = fmaf(p_v(p.x), R_ * t2_, accx); \
    accy = fmaf(p_v(p.y), R_ * t1_, accy); }

// ---------------------------------------------------------------------------
// Shared GEMM body (MFMA, inline prev-layer BN for bf16 path, QUARTER-MAJOR
// outputs): Kq stores e^-k; QVq packs (e^-q | v); Hq stores skip+bias.
// exp via raw v_exp_f32: e^-(acc+b) = 2^fma(acc,-log2e, -b*log2e).
// prevStats is 4-way replicated (SREP x 128) — summed here.
// F32=1: layer-0 path (fp32 X input, no BN fold).
// ---------------------------------------------------------------------------
template<int F32>
__device__ __forceinline__ void gemm_body(
    const void* __restrict__ HinV,
    const bf16x8* __restrict__ whbuf, const bf16x8* __restrict__ wlbuf,
    const float* __restrict__ bk, const float* __restrict__ bq,
    const float* __restrict__ bv, const float* __restrict__ bs,
    const float* __restrict__ prevStats,
    const float* __restrict__ prevGamma, const float* __restrict__ prevBeta,
    unsigned short* __restrict__ Kq, unsigned int* __restrict__ QVq,
    unsigned short* __restrict__ Hq, const int gb)
{
    __shared__ unsigned int sA[GROWS * SAW];   // packed split-bf16 A
    __shared__ float sAB[128];                 // a[64], b[64]
    const int tid = threadIdx.x;

    if (!F32) {
        if (tid < 64) {
            float s1 = 0.f, s2 = 0.f;
#pragma unroll
            for (int r = 0; r < SREP; r++) {
                s1 += prevStats[r * 128 + tid];
                s2 += prevStats[r * 128 + 64 + tid];
            }
            const float invN = 1.0f / (float)NN;
            const float mean = s1 * invN;
            const float var  = s2 * invN - mean * mean;
            const float inv  = rsqrtf(var + BN_EPS);
            const float a = inv * prevGamma[tid];
            sAB[tid]      = a;
            sAB[64 + tid] = prevBeta[tid] - mean * a;
        }
        __syncthreads();
    }

    const int row0 = gb * GROWS;
    if (F32) {
        const float* X = (const float*)HinV;
        for (int i = tid; i < GROWS * 16; i += 256) {
            const int row = i >> 4;
            const int k4  = (i & 15) * 4;
            float4 x = make_float4(0.f, 0.f, 0.f, 0.f);
            if (row0 + row < NN)
                x = *(const float4*)(X + (size_t)(row0 + row) * DD + k4);
            const float xs[4] = {x.x, x.y, x.z, x.w};
            unsigned int* dst = &sA[row * SAW + k4];
#pragma unroll
            for (int j = 0; j < 4; j++) {
                short hs, ls;
                split_bf16(xs[j], hs, ls);
                dst[j] = ((unsigned int)(unsigned short)hs << 16) | (unsigned short)ls;
            }
        }
    } else {
        const unsigned short* Hin = (const unsigned short*)HinV;
        for (int i = tid; i < GROWS * 8; i += 256) {
            const int row = i >> 3;
            const int cb  = (i & 7) * 8;   // col base: 0,8,..,56
            const int q   = cb >> 4;
            const int o16 = cb & 15;       // 0 or 8
            uint4 v = make_uint4(0u, 0u, 0u, 0u);
            if (row0 + row < NN)
                v = *(const uint4*)&Hin[((size_t)q * NN + row0 + row) * 16 + o16];
            const unsigned ws[4] = {v.x, v.y, v.z, v.w};
            unsigned int* dst = &sA[row * SAW + cb];
#pragma unroll
            for (int j = 0; j < 4; j++) {
                const float x0 = bf2f((unsigned short)(ws[j] & 0xFFFFu));
                const float x1 = bf2f((unsigned short)(ws[j] >> 16));
                const int c0 = cb + 2 * j, c1 = cb + 2 * j + 1;
                short hs, ls;
                split_bf16(fmaf(x0, sAB[c0], sAB[64 + c0]), hs, ls);
                dst[2 * j] = ((unsigned int)(unsigned short)hs << 16) | (unsigned short)ls;
                split_bf16(fmaf(x1, sAB[c1], sAB[64 + c1]), hs, ls);
                dst[2 * j + 1] = ((unsigned int)(unsigned short)hs << 16) | (unsigned short)ls;
            }
        }
    }

    const int wave = tid >> 6;    // column tile == quarter
    const int lane = tid & 63;
    const int n15  = lane & 15;
    const int g    = lane >> 4;
    const int col  = wave * 16 + n15;

    bf16x8 wh[4][2], wl[4][2];
    {
        const int base = wave * 64 + lane;
#pragma unroll
        for (int m = 0; m < 4; m++)
#pragma unroll
            for (int c = 0; c < 2; c++) {
                const int idx = m * 512 + c * 256 + base;
                wh[m][c] = whbuf[idx];
                wl[m][c] = wlbuf[idx];
            }
    }

    const float nbk = -bk[col] * L2E;   // folded: 2^(acc*-L2E + nbk) = e^-(acc+bk)
    const float nbq = -bq[col] * L2E;
    const float bvc = bv[col], bsc = bs[col];
    __syncthreads();

#pragma unroll 1
    for (int t = 0; t < GT; t++) {
        const int rowbase = row0 + t * 16;
        if (rowbase >= NN) break;   // NN % 16 == 0

        bf16x8 ah[2], al[2];
#pragma unroll
        for (int c = 0; c < 2; c++) {
            const uint4 u0 = *(const uint4*)&sA[(t * 16 + n15) * SAW + g * 8 + 32 * c];
            const uint4 u1 = *(const uint4*)&sA[(t * 16 + n15) * SAW + g * 8 + 32 * c + 4];
            const unsigned int us[8] = {u0.x, u0.y, u0.z, u0.w, u1.x, u1.y, u1.z, u1.w};
            bf16x8 h, l;
#pragma unroll
            for (int j = 0; j < 8; j++) {
                h[j] = (short)(us[j] >> 16);
                l[j] = (short)(us[j] & 0xFFFFu);
            }
            ah[c] = h; al[c] = l;
        }

        f32x4 acc[4];
#pragma unroll
        for (int m = 0; m < 4; m++) acc[m] = (f32x4){0.f, 0.f, 0.f, 0.f};

#pragma unroll
        for (int c = 0; c < 2; c++) {
#pragma unroll
            for (int m = 0; m < 4; m++) {
                acc[m] = __builtin_amdgcn_mfma_f32_16x16x32_bf16(ah[c], wh[m][c], acc[m], 0, 0, 0);
                acc[m] = __builtin_amdgcn_mfma_f32_16x16x32_bf16(al[c], wh[m][c], acc[m], 0, 0, 0);
                acc[m] = __builtin_amdgcn_mfma_f32_16x16x32_bf16(ah[c], wl[m][c], acc[m], 0, 0, 0);
            }
        }

#pragma unroll
        for (int r = 0; r < 4; r++) {
            const int row = rowbase + g * 4 + r;
            const size_t o  = ((size_t)wave * NN  + row) * 16 + n15;
            const size_t oq = ((size_t)wave * NNS + row) * 16 + n15;
            Kq[o]   = f2bf(__builtin_amdgcn_exp2f(fmaf(acc[0][r], -L2E, nbk)));
            QVq[oq] = pack_bf16x2(__builtin_amdgcn_exp2f(fmaf(acc[1][r], -L2E, nbq)),
                                  acc[2][r] + bvc);
            Hq[o]   = f2bf(acc[3][r] + bsc);
        }
    }
}

// ---------------------------------------------------------------------------
// Fused prep: deg histogram (blocks 0..3124) + W-fragment split (blocks
// 3125..3164) + QVq sentinel-row zeroing. Independent work, one launch.
// ---------------------------------------------------------------------------
__global__ __launch_bounds__(256) void prep_kernel(
    const int* __restrict__ ei, int* __restrict__ deg,
    const float* __restrict__ Wk, const float* __restrict__ Wq,
    const float* __restrict__ Wv, const float* __restrict__ Ws,
    bf16x8* __restrict__ whbuf, bf16x8* __restrict__ wlbuf,
    unsigned int* __restrict__ QVq)
{
    const int bid = blockIdx.x;
    if (bid < DEG_BLOCKS) {
        const int e = bid * 256 + threadIdx.x;
        if (e < NE) atomicAdd(&deg[ei[NE + e]], 1);
        return;
    }
    if (bid == DEG_BLOCKS && threadIdx.x < 64) {
        const int q = threadIdx.x >> 4, c = threadIdx.x & 15;
        QVq[((size_t)q * NNS + NN) * 16 + c] = 0u;   // sentinel row: e^-q=0, v=0
    }
    const int t = (bid - DEG_BLOCKS) * 256 + threadIdx.x;
    if (t >= NL * 2048) return;
    const int lane = t & 63;
    const int w    = (t >> 6) & 3;
    const int c    = (t >> 8) & 1;
    const int m    = (t >> 9) & 3;
    const int l    = t >> 11;

    const float* Wm4[4] = {Wk, Wq, Wv, Ws};
    const float* W = Wm4[m] + l * 4096;
    const int col = w * 16 + (lane & 15);
    const int g   = lane >> 4;

    bf16x8 h, lo;
#pragma unroll
    for (int j = 0; j < 8; j++) {
        const int k = g * 8 + j + 32 * c;
        short hs, ls;
        split_bf16(W[k * DD + col], hs, ls);
        h[j] = hs; lo[j] = ls;
    }
    whbuf[t] = h;
    wlbuf[t] = lo;
}

// ---------------------------------------------------------------------------
// Scans over PADDED degrees (multiple of 8).
// ---------------------------------------------------------------------------
__global__ __launch_bounds__(256) void scan_partial_kernel(
    const int* __restrict__ deg, int* __restrict__ psums)
{
    __shared__ int ls[256];
    const int i = blockIdx.x * 256 + threadIdx.x;
    ls[threadIdx.x] = (i < NN) ? PADDEG(deg[i]) : 0;
    __syncthreads();
    for (int off = 128; off > 0; off >>= 1) {
        if (threadIdx.x < off) ls[threadIdx.x] += ls[threadIdx.x + off];
        __syncthreads();
    }
    if (threadIdx.x == 0) psums[blockIdx.x] = ls[0];
}

// Wave-parallel exclusive scan over NCHUNK partials. 64 lanes x 4 chunks.
__global__ __launch_bounds__(64) void scan_offsets_kernel(
    int* __restrict__ psums, int* __restrict__ rowst)
{
    const int lane = threadIdx.x;
    const int base = lane * 4;
    int v[4];
    int s = 0;
#pragma unroll
    for (int j = 0; j < 4; j++) {
        v[j] = (base + j < NCHUNK) ? psums[base + j] : 0;
        s += v[j];
    }
    int incl = s;
    for (int off = 1; off < 64; off <<= 1) {
        const int t = __shfl_up(incl, off);
        if (lane >= off) incl += t;
    }
    const int total = __shfl(incl, 63);
    int run = incl - s;   // exclusive
#pragma unroll
    for (int j = 0; j < 4; j++) {
        if (base + j < NCHUNK) psums[base + j] = run;
        run += v[j];
    }
    if (lane == 0) rowst[NN] = total;  // padded edge total
}

__global__ __launch_bounds__(256) void scan_final_kernel(
    const int* __restrict__ deg, const int* __restrict__ psums,
    int* __restrict__ rowst, int* __restrict__ cursor)
{
    __shared__ int ls[256];
    const int i = blockIdx.x * 256 + threadIdx.x;
    const int x = (i < NN) ? PADDEG(deg[i]) : 0;
    ls[threadIdx.x] = x;
    __syncthreads();
    for (int off = 1; off < 256; off <<= 1) {
        int v = (threadIdx.x >= off) ? ls[threadIdx.x - off] : 0;
        __syncthreads();
        ls[threadIdx.x] += v;
        __syncthreads();
    }
    if (i < NN) {
        const int excl = psums[blockIdx.x] + ls[threadIdx.x] - x;
        rowst[i]  = excl;
        cursor[i] = excl;
    }
}

// ---------------------------------------------------------------------------
// Fused gemm0 + RANGE-PARTITIONED CSR fill + sentinel pad (R4-proven).
// ---------------------------------------------------------------------------
__global__ __launch_bounds__(256) void gfp_kernel(
    const float* __restrict__ X,
    const bf16x8* __restrict__ whbuf, const bf16x8* __restrict__ wlbuf,
    const float* __restrict__ bk, const float* __restrict__ bq,
    const float* __restrict__ bv, const float* __restrict__ bs,
    unsigned short* __restrict__ Kq, unsigned int* __restrict__ QVq,
    unsigned short* __restrict__ Hq,
    const int* __restrict__ ei, int* __restrict__ cursor,
    const int* __restrict__ rowst, const int* __restrict__ deg,
    unsigned short* __restrict__ csr16)
{
    const int bid = blockIdx.x;
    if (bid < GEMM_BLOCKS) {
        gemm_body<1>(X, whbuf, wlbuf, bk, bq, bv, bs,
                     nullptr, nullptr, nullptr, Kq, QVq, Hq, bid);
        return;
    }
    if (bid < GEMM_BLOCKS + FILLP_BLOCKS) {
        const int fid = bid - GEMM_BLOCKS;
        const int r   = bid & 7;            // dst-range == XCD (heuristic)
        const int o   = fid >> 3;           // edge chunk ordinal
        const int lo  = r * NRANGE;
        const int hi  = lo + NRANGE;
        const int e0  = o * FCHK;
        const int e1  = min(e0 + FCHK, NE);
        for (int e = e0 + threadIdx.x; e < e1; e += 256) {
            const int dst = ei[NE + e];
            if (dst >= lo && dst < hi) {
                const int src = ei[e];      // < 50000 < 65536 -> u16 exact
                csr16[atomicAdd(&cursor[dst], 1)] = (unsigned short)src;
            }
        }
        return;
    }
    const int n = (bid - GEMM_BLOCKS - FILLP_BLOCKS) * 256 + threadIdx.x;
    if (n >= NN) return;
    const int end = rowst[n + 1];
    for (int i = rowst[n] + deg[n]; i < end; i++) csr16[i] = (unsigned short)NN;
}

// ---------------------------------------------------------------------------
// gemm for layers 1..4 (bf16 input, prev-layer BN folded from replicated
// stats).
// ---------------------------------------------------------------------------
__global__ __launch_bounds__(256) void gemm4_mfma(
    const void* __restrict__ HinV,
    const bf16x8* __restrict__ whbuf, const bf16x8* __restrict__ wlbuf,
    const float* __restrict__ bk, const float* __restrict__ bq,
    const float* __restrict__ bv, const float* __restrict__ bs,
    const float* __restrict__ prevStats,
    const float* __restrict__ prevGamma, const float* __restrict__ prevBeta,
    unsigned short* __restrict__ Kq, unsigned int* __restrict__ QVq,
    unsigned short* __restrict__ Hq)
{
    gemm_body<0>(HinV, whbuf, wlbuf, bk, bq, bv, bs,
                 prevStats, prevGamma, prevBeta, Kq, QVq, Hq, blockIdx.x);
}

// ---------------------------------------------------------------------------
// Column-quarter XCD-partitioned gather — R4 body (best measured, 55.1 us)
// with ONE change: stats atomics go to a per-block REPLICA ((bid>>3)&3 of
// SREP=4), cutting same-address atomic serialization 4x (was 1564 blocks
// RMW-ing the same 32 addresses per quarter — a per-block retirement tail).
// ---------------------------------------------------------------------------
#define GATHER_BLOCKS (8 * 782)   // 6256
__global__ __launch_bounds__(256) void gather_kernel(
    const int* __restrict__ rowst, const unsigned short* __restrict__ csr16,
    const unsigned short* __restrict__ Kq, const unsigned int* __restrict__ QVq,
    unsigned short* Hq, float* __restrict__ stats)
{
    const int tid  = threadIdx.x;
    const int wv   = tid >> 6;
    const int lane = tid & 63;
    const int eoff = lane >> 3;     // edge slot 0..7
    const int cp   = lane & 7;      // column pair (cols 2cp, 2cp+1)

    const int j       = blockIdx.x;
    const int xcd     = j & 7;
    const int quarter = xcd >> 1;
    const int half    = xcd & 1;
    const int nodebase = ((j >> 3) * 2 + half) * 32 + wv * 8;

    const unsigned* Kq32 = (const unsigned*)(Kq + (size_t)quarter * NN * 16);
    const uint2*    Qq2  = (const uint2*)(QVq + (size_t)quarter * NNS * 16);
    unsigned*       Hq32 = (unsigned*)(Hq + (size_t)quarter * NN * 16);

    float se = 0.f, s2e = 0.f, so = 0.f, s2o = 0.f;   // stats cols 2cp / 2cp+1

    int e00 = rowst[min(nodebase, NN)];   // carried: e00(t+1) = e11(t)

    for (int t = 0; t < 4; t++) {
        const int n0 = nodebase + 2 * t;   // even; n1 = n0+1 < NN when n0 < NN
        if (n0 >= NN) break;
        const int n1 = n0 + 1;
        const unsigned ho0 = (unsigned)(n0 * 8 + cp);
        const unsigned ho1 = (unsigned)(n1 * 8 + cp);
        unsigned h0p = 0u, h1p = 0u;
        if (eoff == 0) {                   // exec-masked prefetch of skip term
            h0p = Hq32[ho0];
            h1p = Hq32[ho1];
        }
        const unsigned k0p = Kq32[ho0];    // packed e^-k
        const unsigned k1p = Kq32[ho1];
        const float ek00 = bf2f((unsigned short)(k0p & 0xFFFFu));
        const float ek01 = bf2f((unsigned short)(k0p >> 16));
        const float ek10 = bf2f((unsigned short)(k1p & 0xFFFFu));
        const float ek11 = bf2f((unsigned short)(k1p >> 16));
        const int e01 = rowst[n1], e11 = rowst[n1 + 1];
        int nd0 = (e01 - e00) >> 3;        // padded slot counts
        int nd1 = (e11 - e01) >> 3;
        int ndm = min(nd0, nd1);
        nd0 -= ndm; nd1 -= ndm;
        int b0 = e00, b1 = e01;            // base edge indices (even)
        e00 = e11;                         // carry for next t
        float a00 = 0.f, a01 = 0.f, a10 = 0.f, a11 = 0.f;

        // dual-node main loop: 16 edges/node per iter, 2 u32 csr + 4 uint2
        // QVq loads in flight, 4 rcp per 8 gates.
        while (ndm >= 2) {
            const unsigned s0 = *(const unsigned*)(csr16 + b0 + 2 * eoff);
            const unsigned s1 = *(const unsigned*)(csr16 + b1 + 2 * eoff);
            const uint2 p0a = Qq2[(s0 & 0xFFFFu) * 8u + cp];
            const uint2 p0b = Qq2[(s0 >> 16) * 8u + cp];
            const uint2 p1a = Qq2[(s1 & 0xFFFFu) * 8u + cp];
            const uint2 p1b = Qq2[(s1 >> 16) * 8u + cp];
            GPAIR(ek00, p0a.x, p0b.x, a00);
            GPAIR(ek01, p0a.y, p0b.y, a01);
            GPAIR(ek10, p1a.x, p1b.x, a10);
            GPAIR(ek11, p1a.y, p1b.y, a11);
            b0 += 16; b1 += 16; ndm -= 2;
        }
        if (ndm) {   // one joint slot left (u16 per lane)
            const int s0 = csr16[b0 + eoff];
            const int s1 = csr16[b1 + eoff];
            const uint2 p0 = Qq2[(unsigned)(s0 * 8 + cp)];
            const uint2 p1 = Qq2[(unsigned)(s1 * 8 + cp)];
            GCOLS(ek00, ek01, p0, a00, a01);
            GCOLS(ek10, ek11, p1, a10, a11);
            b0 += 8; b1 += 8;
        }
        while (nd0 >= 2) {   // node-0 surplus, 16-edge steps
            const unsigned s0 = *(const unsigned*)(csr16 + b0 + 2 * eoff);
            const uint2 p0a = Qq2[(s0 & 0xFFFFu) * 8u + cp];
            const uint2 p0b = Qq2[(s0 >> 16) * 8u + cp];
            GPAIR(ek00, p0a.x, p0b.x, a00);
            GPAIR(ek01, p0a.y, p0b.y, a01);
            b0 += 16; nd0 -= 2;
        }
        if (nd0) {
            const int s0 = csr16[b0 + eoff];
            const uint2 p0 = Qq2[(unsigned)(s0 * 8 + cp)];
            GCOLS(ek00, ek01, p0, a00, a01);
        }
        while (nd1 >= 2) {   // node-1 surplus, 16-edge steps
            const unsigned s1 = *(const unsigned*)(csr16 + b1 + 2 * eoff);
            const uint2 p1a = Qq2[(s1 & 0xFFFFu) * 8u + cp];
            const uint2 p1b = Qq2[(s1 >> 16) * 8u + cp];
            GPAIR(ek10, p1a.x, p1b.x, a10);
            GPAIR(ek11, p1a.y, p1b.y, a11);
            b1 += 16; nd1 -= 2;
        }
        if (nd1) {
            const int s1 = csr16[b1 + eoff];
            const uint2 p1 = Qq2[(unsigned)(s1 * 8 + cp)];
            GCOLS(ek10, ek11, p1, a10, a11);
        }

        // combine edge slots: lanes cp, cp+8, ..., cp+56 share columns
        a00 += __shfl_xor(a00, 8);  a00 += __shfl_xor(a00, 16); a00 += __shfl_xor(a00, 32);
        a01 += __shfl_xor(a01, 8);  a01 += __shfl_xor(a01, 16); a01 += __shfl_xor(a01, 32);
        a10 += __shfl_xor(a10, 8);  a10 += __shfl_xor(a10, 16); a10 += __shfl_xor(a10, 32);
        a11 += __shfl_xor(a11, 8);  a11 += __shfl_xor(a11, 16); a11 += __shfl_xor(a11, 32);

        if (eoff == 0) {
            const float o00 = fmaxf(bf2f((unsigned short)(h0p & 0xFFFFu)) + a00, 0.f);
            const float o01 = fmaxf(bf2f((unsigned short)(h0p >> 16))     + a01, 0.f);
            const float o10 = fmaxf(bf2f((unsigned short)(h1p & 0xFFFFu)) + a10, 0.f);
            const float o11 = fmaxf(bf2f((unsigned short)(h1p >> 16))     + a11, 0.f);
            const unsigned short b00 = f2bf(o00), b01 = f2bf(o01);
            const unsigned short b10 = f2bf(o10), b11 = f2bf(o11);
            Hq32[ho0] = ((unsigned)b01 << 16) | b00;
            Hq32[ho1] = ((unsigned)b11 << 16) | b10;
            const float r00 = bf2f(b00), r01 = bf2f(b01);
            const float r10 = bf2f(b10), r11 = bf2f(b11);
            se  += r00 + r10;  s2e += r00 * r00 + r10 * r10;
            so  += r01 + r11;  s2o += r01 * r01 + r11 * r11;
        }
    }

    __shared__ float ls[64], ls2[64];   // 4 waves x 16 cols
    if (eoff == 0) {
        ls[wv * 16 + 2 * cp]      = se;  ls2[wv * 16 + 2 * cp]      = s2e;
        ls[wv * 16 + 2 * cp + 1]  = so;  ls2[wv * 16 + 2 * cp + 1]  = s2o;
    }
    __syncthreads();
    if (tid < 16) {
        const int rep = (j >> 3) & (SREP - 1);   // stats replica
        const float a = ls[tid] + ls[16 + tid] + ls[32 + tid] + ls[48 + tid];
        const float b = ls2[tid] + ls2[16 + tid] + ls2[32 + tid] + ls2[48 + tid];
        atomicAdd(&stats[rep * 128 + quarter * 16 + tid], a);
        atomicAdd(&stats[rep * 128 + 64 + quarter * 16 + tid], b);
    }
}

// ---------------------------------------------------------------------------
// Pooled segment-sum over quarter-major bf16 H (batch sorted). u32 loads:
// 32 threads per 64-row chunk, each thread owns 2 adjacent cols; 8 chunks
// per 256-thread block.
// ---------------------------------------------------------------------------
#define POOL_ROWS 64
__global__ __launch_bounds__(256) void pool_kernel(
    const unsigned short* __restrict__ Hq, const int* __restrict__ batch,
    float* __restrict__ psum, float* __restrict__ pcnt)
{
    const int sub = threadIdx.x >> 5;   // chunk 0..7
    const int c   = threadIdx.x & 31;   // col-pair id
    const int q   = c >> 3;             // quarter
    const int p   = c & 7;              // pair within quarter (cols 2p, 2p+1)
    const int r0 = (blockIdx.x * 8 + sub) * POOL_ROWS;
    if (r0 >= NN) return;
    const int r1 = min(r0 + POOL_ROWS, NN);
    const unsigned* Hqq = (const unsigned*)(Hq + (size_t)q * NN * 16);
    const int col0 = q * 16 + 2 * p;

    int cur = batch[r0];
    float acc0 = 0.f, acc1 = 0.f, cnt = 0.f;
    for (int r = r0; r < r1; r++) {
        const int g = batch[r];
        if (g != cur) {
            atomicAdd(&psum[cur * DD + col0], acc0);
            atomicAdd(&psum[cur * DD + col0 + 1], acc1);
            if (c == 0) atomicAdd(&pcnt[cur], cnt);
            acc0 = 0.f; acc1 = 0.f; cnt = 0.f; cur = g;
        }
        const unsigned hv = Hqq[(size_t)r * 8 + p];
        acc0 += bf2f((unsigned short)(hv & 0xFFFFu));
        acc1 += bf2f((unsigned short)(hv >> 16));
        cnt += 1.f;
    }
    atomicAdd(&psum[cur * DD + col0], acc0);
    atomicAdd(&psum[cur * DD + col0 + 1], acc1);
    if (c == 0) atomicAdd(&pcnt[cur], cnt);
}

// ---------------------------------------------------------------------------
// Final: pooled mean -> folded last-layer BN affine (replicated stats) ->
// logits -> softmax.
// ---------------------------------------------------------------------------
__global__ __launch_bounds__(256) void final_kernel(
    const float* __restrict__ psum, const float* __restrict__ pcnt,
    const float* __restrict__ stats,
    const float* __restrict__ gamma, const float* __restrict__ beta,
    const float* __restrict__ Wlin, const float* __restrict__ blin,
    float* __restrict__ out)
{
    const int g = blockIdx.x * blockDim.x + threadIdx.x;
    if (g >= NG) return;

    const float invc = 1.0f / fmaxf(pcnt[g], 1.0f);
    const float invN = 1.0f / (float)NN;
    float p[DD];
#pragma unroll
    for (int d = 0; d < DD; d++) {
        float s1 = 0.f, s2 = 0.f;
#pragma unroll
        for (int r = 0; r < SREP; r++) {
            s1 += stats[r * 128 + d];
            s2 += stats[r * 128 + 64 + d];
        }
        const float mean = s1 * invN;
        const float var  = s2 * invN - mean * mean;
        const float inv  = rsqrtf(var + BN_EPS);
        const float a = inv * gamma[d];
        const float b = beta[d] - mean * a;
        p[d] = fmaf(psum[g * DD + d] * invc, a, b);
    }

    float logits[NC];
    float m = -1e30f;
#pragma unroll
    for (int c = 0; c < NC; c++) {
        float acc = blin[c];
#pragma unroll
        for (int d = 0; d < DD; d++) acc = fmaf(p[d], Wlin[d * NC + c], acc);
        logits[c] = acc;
        m = fmaxf(m, acc);
    }
    float sum = 0.f;
#pragma unroll
    for (int c = 0; c < NC; c++) {
        logits[c] = __expf(logits[c] - m);
        sum += logits[c];
    }
    const float inv = 1.f / sum;
#pragma unroll
    for (int c = 0; c < NC; c++) out[g * NC + c] = logits[c] * inv;
}

// ---------------------------------------------------------------------------
extern "C" void kernel_launch(void* const* d_in, const int* in_sizes, int n_in,
                              void* d_out, int out_size, void* d_ws, size_t ws_size,
                              hipStream_t stream)
{
    const float* X     = (const float*)d_in[0];
    const int*   ei    = (const int*)d_in[1];
    const int*   batch = (const int*)d_in[2];
    const float* Wk    = (const float*)d_in[3];
    const float* Wq    = (const float*)d_in[4];
    const float* Wv    = (const float*)d_in[5];
    const float* Ws    = (const float*)d_in[6];
    const float* bk    = (const float*)d_in[7];
    const float* bq    = (const float*)d_in[8];
    const float* bv    = (const float*)d_in[9];
    const float* bconv = (const float*)d_in[10];
    const float* gamma = (const float*)d_in[11];
    const float* beta  = (const float*)d_in[12];
    const float* Wlin  = (const float*)d_in[13];
    const float* blin  = (const float*)d_in[14];
    float* out = (float*)d_out;

    const size_t M  = (size_t)NN * DD;        // == 4 * NN * 16
    const size_t MQ = (size_t)4 * NNS * 16;   // QVq uints (padded stride)
    unsigned short* Kq  = (unsigned short*)d_ws;      // M bf16 (e^-k), quarter-major
    unsigned int*   QVq = (unsigned int*)(Kq + M);    // MQ packed (e^-q|v), stride NNS
    unsigned short* H0q = (unsigned short*)(QVq + MQ);// M bf16, quarter-major
    unsigned short* H1q = H0q + M;                    // M bf16
    // --- contiguous zero-init region ---
    int*   deg   = (int*)(H1q + M);                   // NN
    float* psum  = (float*)(deg + NN);                // NG*DD
    float* pcnt  = psum + (size_t)NG * DD;            // NG
    float* stats = pcnt + NG;                         // NL*SSTR (4-replica)
    // --- end zero region ---
    int* rowst  = (int*)(stats + NL * SSTR);          // NN+1
    int* cursor = rowst + NN + 1;                     // NN
    int* psums  = cursor + NN;                        // 256
    unsigned short* csr16 = (unsigned short*)(psums + 256);  // NE + 8*NN u16 (padded)
    bf16x8* whbuf = (bf16x8*)(csr16 + NE + 8 * NN);   // NL*2048 frags
    bf16x8* wlbuf = whbuf + NL * 2048;

    const size_t zero_bytes = (size_t)(NN + NG * DD + NG + NL * SSTR) * 4;
    hipMemsetAsync(deg, 0, zero_bytes, stream);

    // ---- fused deg histogram + W fragment prep + sentinel zeroing ----
    prep_kernel<<<DEG_BLOCKS + WPREP_BLOCKS, 256, 0, stream>>>(
        ei, deg, Wk, Wq, Wv, Ws, whbuf, wlbuf, QVq);

    // ---- scans over padded degrees ----
    scan_partial_kernel<<<NCHUNK, 256, 0, stream>>>(deg, psums);
    scan_offsets_kernel<<<1, 64, 0, stream>>>(psums, rowst);
    scan_final_kernel<<<NCHUNK, 256, 0, stream>>>(deg, psums, rowst, cursor);

    // ---- fused layer-0 gemm + range-partitioned CSR fill + sentinel pad ----
    gfp_kernel<<<GEMM_BLOCKS + FILLP_BLOCKS + PAD_BLOCKS, 256, 0, stream>>>(
        X, whbuf, wlbuf, bk, bq, bv, bconv,
        Kq, QVq, H0q, ei, cursor, rowst, deg, csr16);

    // ---- layers ----
    gather_kernel<<<GATHER_BLOCKS, 256, 0, stream>>>(
        rowst, csr16, Kq, QVq, H0q, stats);
    const void* hin = (const void*)H0q;
    for (int l = 1; l < NL; l++) {
        unsigned short* hout = (l & 1) ? H1q : H0q;
        gemm4_mfma<<<GEMM_BLOCKS, 256, 0, stream>>>(
            hin, whbuf + l * 2048, wlbuf + l * 2048,
            bk + l * 64, bq + l * 64, bv + l * 64, bconv + l * 64,
            stats + (l - 1) * SSTR, gamma + (l - 1) * 64, beta + (l - 1) * 64,
            Kq, QVq, hout);
        gather_kernel<<<GATHER_BLOCKS, 256, 0, stream>>>(
            rowst, csr16, Kq, QVq, hout, stats + l * SSTR);
        hin = (const void*)hout;
    }

    pool_kernel<<<(NN + 8 * POOL_ROWS - 1) / (8 * POOL_ROWS), 256, 0, stream>>>(
        (const unsigned short*)hin, batch, psum, pcnt);
    final_kernel<<<1, 256, 0, stream>>>(
        psum, pcnt, stats + 4 * SSTR, gamma + 4 * 64, beta + 4 * 64, Wlin, blin, out);
}

// Round 9
// 455.345 us; speedup vs baseline: 1.2120x; 1.1388x over previous
//
#include <hip/hip_runtime.h>

#define NN 50000
#define NE 800000
#define DD 64
#define NL 5
#define NG 256
#define NC 10
#define BN_EPS 1e-5f
#define NCHUNK ((NN + 255) / 256)   // 196
#define GROWS 128                    // rows per gemm block (R4-proven)
#define GT (GROWS / 16)              // 16-row tiles per block
#define SAW 68                       // staged-A row stride (uints)
#define GEMM_BLOCKS ((NN + GROWS - 1) / GROWS)   // 391
#define NNS (NN + 8)                 // QVq per-quarter row stride (sentinel at row NN)
#define PADDEG(d) (((d) + 7) & ~7)   // csr segment padded to multiple of 8
#define DEG_BLOCKS ((NE + 255) / 256)        // 3125
#define WPREP_BLOCKS ((NL * 2048 + 255) / 256)  // 40
#define FCHK 2048                            // edges per fill chunk
#define FCHUNKS ((NE + FCHK - 1) / FCHK)     // 391
#define FILLP_BLOCKS (8 * FCHUNKS)           // 3128 (8 dst-ranges x chunks)
#define NRANGE (NN / 8)                      // 6250 nodes per dst-range
#define PAD_BLOCKS NCHUNK                    // 196
#define SREP 4                               // stats replicas (atomic contention /4)
#define SSTR (SREP * 128)                    // per-layer stats stride (512 floats)
#define L2E 1.4426950408889634f              // log2(e)

typedef __attribute__((ext_vector_type(8))) short bf16x8;
typedef __attribute__((ext_vector_type(4))) float f32x4;

__device__ inline float bf2f(unsigned short u) {
    return __uint_as_float((unsigned)u << 16);
}
__device__ inline unsigned short f2bf(float x) {   // RNE
    unsigned u = __float_as_uint(x);
    u += 0x7FFFu + ((u >> 16) & 1u);
    return (unsigned short)(u >> 16);
}

// Pack two floats as bf16 (RNE) into one uint: low16 = a, high16 = b.
__device__ inline unsigned int pack_bf16x2(float a, float b) {
    unsigned int ua = __float_as_uint(a);
    unsigned int ub = __float_as_uint(b);
    ua += 0x7FFFu + ((ua >> 16) & 1u);
    ub += 0x7FFFu + ((ub >> 16) & 1u);
    return (ub & 0xFFFF0000u) | (ua >> 16);
}

// Split fp32 into bf16 hi (RTZ) + bf16 lo (residual). hi+lo ~ x to ~2^-17.
__device__ inline void split_bf16(float x, short& h, short& l) {
    const unsigned u  = __float_as_uint(x);
    const unsigned hb = u & 0xFFFF0000u;
    h = (short)(hb >> 16);
    const float lo = x - __uint_as_float(hb);
    l = (short)(__float_as_uint(lo) >> 16);
}

// packed (e^-q | v) accessors: low16 = e^-q, high16 = v.
__device__ inline float p_eq(unsigned p) { return __uint_as_float(p << 16); }
__device__ inline float p_v(unsigned p)  { return __uint_as_float(p & 0xFFFF0000u); }

// Two gates sharing one ek (batched reciprocal, 1 rcp for 2 gates):
// v1/t1 + v2/t2 = (v1*t2 + v2*t1) * rcp(t1*t2).  [numerics proven in R2]
#define GPAIR(ek, pa, pb, acc) { \
    const float t1_ = fmaf(ek, p_eq(pa), 1.f); \
    const float t2_ = fmaf(ek, p_eq(pb), 1.f); \
    const float R_  = __builtin_amdgcn_rcpf(t1_ * t2_); \
    acc = fmaf(fmaf(p_v(pb), t1_, p_v(pa) * t2_), R_, acc); }

// Two gates with different ek (one uint2's two cols): inverse recovery,
// R=rcp(t1*t2); 1/t1=R*t2; 1/t2=R*t1.  [numerics proven in R2]
#define GCOLS(ekx, eky, p, accx, accy) { \
    const float t1_ = fmaf(ekx, p_eq(p.x), 1.f); \
    const float t2_ = fmaf(eky, p_eq(p.y), 1.f); \
    const float R_  = __builtin_amdgcn_rcpf(t1_ * t2_); \
    accx = fmaf(p_v(p.x), R_ * t2_, accx); \
    accy = fmaf(p_v(p.y), R_ * t1_, accy); }

// ---------------------------------------------------------------------------
// Shared GEMM body (MFMA, inline prev-layer BN for bf16 path, QUARTER-MAJOR
// outputs): Kq stores e^-k; QVq packs (e^-q | v); Hq stores skip+bias.
// exp via raw v_exp_f32: e^-(acc+b) = 2^fma(acc,-log2e, -b*log2e).
// prevStats is 4-way replicated (SREP x 128) — summed here.
// F32=1: layer-0 path (fp32 X input, no BN fold).
// ---------------------------------------------------------------------------
template<int F32>
__device__ __forceinline__ void gemm_body(
    const void* __restrict__ HinV,
    const bf16x8* __restrict__ whbuf, const bf16x8* __restrict__ wlbuf,
    const float* __restrict__ bk, const float* __restrict__ bq,
    const float* __restrict__ bv, const float* __restrict__ bs,
    const float* __restrict__ prevStats,
    const float* __restrict__ prevGamma, const float* __restrict__ prevBeta,
    unsigned short* __restrict__ Kq, unsigned int* __restrict__ QVq,
    unsigned short* __restrict__ Hq, const int gb)
{
    __shared__ unsigned int sA[GROWS * SAW];   // packed split-bf16 A
    __shared__ float sAB[128];                 // a[64], b[64]
    const int tid = threadIdx.x;

    if (!F32) {
        if (tid < 64) {
            float s1 = 0.f, s2 = 0.f;
#pragma unroll
            for (int r = 0; r < SREP; r++) {
                s1 += prevStats[r * 128 + tid];
                s2 += prevStats[r * 128 + 64 + tid];
            }
            const float invN = 1.0f / (float)NN;
            const float mean = s1 * invN;
            const float var  = s2 * invN - mean * mean;
            const float inv  = rsqrtf(var + BN_EPS);
            const float a = inv * prevGamma[tid];
            sAB[tid]      = a;
            sAB[64 + tid] = prevBeta[tid] - mean * a;
        }
        __syncthreads();
    }

    const int row0 = gb * GROWS;
    if (F32) {
        const float* X = (const float*)HinV;
        for (int i = tid; i < GROWS * 16; i += 256) {
            const int row = i >> 4;
            const int k4  = (i & 15) * 4;
            float4 x = make_float4(0.f, 0.f, 0.f, 0.f);
            if (row0 + row < NN)
                x = *(const float4*)(X + (size_t)(row0 + row) * DD + k4);
            const float xs[4] = {x.x, x.y, x.z, x.w};
            unsigned int* dst = &sA[row * SAW + k4];
#pragma unroll
            for (int j = 0; j < 4; j++) {
                short hs, ls;
                split_bf16(xs[j], hs, ls);
                dst[j] = ((unsigned int)(unsigned short)hs << 16) | (unsigned short)ls;
            }
        }
    } else {
        const unsigned short* Hin = (const unsigned short*)HinV;
        for (int i = tid; i < GROWS * 8; i += 256) {
            const int row = i >> 3;
            const int cb  = (i & 7) * 8;   // col base: 0,8,..,56
            const int q   = cb >> 4;
            const int o16 = cb & 15;       // 0 or 8
            uint4 v = make_uint4(0u, 0u, 0u, 0u);
            if (row0 + row < NN)
                v = *(const uint4*)&Hin[((size_t)q * NN + row0 + row) * 16 + o16];
            const unsigned ws[4] = {v.x, v.y, v.z, v.w};
            unsigned int* dst = &sA[row * SAW + cb];
#pragma unroll
            for (int j = 0; j < 4; j++) {
                const float x0 = bf2f((unsigned short)(ws[j] & 0xFFFFu));
                const float x1 = bf2f((unsigned short)(ws[j] >> 16));
                const int c0 = cb + 2 * j, c1 = cb + 2 * j + 1;
                short hs, ls;
                split_bf16(fmaf(x0, sAB[c0], sAB[64 + c0]), hs, ls);
                dst[2 * j] = ((unsigned int)(unsigned short)hs << 16) | (unsigned short)ls;
                split_bf16(fmaf(x1, sAB[c1], sAB[64 + c1]), hs, ls);
                dst[2 * j + 1] = ((unsigned int)(unsigned short)hs << 16) | (unsigned short)ls;
            }
        }
    }

    const int wave = tid >> 6;    // column tile == quarter
    const int lane = tid & 63;
    const int n15  = lane & 15;
    const int g    = lane >> 4;
    const int col  = wave * 16 + n15;

    bf16x8 wh[4][2], wl[4][2];
    {
        const int base = wave * 64 + lane;
#pragma unroll
        for (int m = 0; m < 4; m++)
#pragma unroll
            for (int c = 0; c < 2; c++) {
                const int idx = m * 512 + c * 256 + base;
                wh[m][c] = whbuf[idx];
                wl[m][c] = wlbuf[idx];
            }
    }

    const float nbk = -bk[col] * L2E;   // folded: 2^(acc*-L2E + nbk) = e^-(acc+bk)
    const float nbq = -bq[col] * L2E;
    const float bvc = bv[col], bsc = bs[col];
    __syncthreads();

#pragma unroll 1
    for (int t = 0; t < GT; t++) {
        const int rowbase = row0 + t * 16;
        if (rowbase >= NN) break;   // NN % 16 == 0

        bf16x8 ah[2], al[2];
#pragma unroll
        for (int c = 0; c < 2; c++) {
            const uint4 u0 = *(const uint4*)&sA[(t * 16 + n15) * SAW + g * 8 + 32 * c];
            const uint4 u1 = *(const uint4*)&sA[(t * 16 + n15) * SAW + g * 8 + 32 * c + 4];
            const unsigned int us[8] = {u0.x, u0.y, u0.z, u0.w, u1.x, u1.y, u1.z, u1.w};
            bf16x8 h, l;
#pragma unroll
            for (int j = 0; j < 8; j++) {
                h[j] = (short)(us[j] >> 16);
                l[j] = (short)(us[j] & 0xFFFFu);
            }
            ah[c] = h; al[c] = l;
        }

        f32x4 acc[4];
#pragma unroll
        for (int m = 0; m < 4; m++) acc[m] = (f32x4){0.f, 0.f, 0.f, 0.f};

#pragma unroll
        for (int c = 0; c < 2; c++) {
#pragma unroll
            for (int m = 0; m < 4; m++) {
                acc[m] = __builtin_amdgcn_mfma_f32_16x16x32_bf16(ah[c], wh[m][c], acc[m], 0, 0, 0);
                acc[m] = __builtin_amdgcn_mfma_f32_16x16x32_bf16(al[c], wh[m][c], acc[m], 0, 0, 0);
                acc[m] = __builtin_amdgcn_mfma_f32_16x16x32_bf16(ah[c], wl[m][c], acc[m], 0, 0, 0);
            }
        }

#pragma unroll
        for (int r = 0; r < 4; r++) {
            const int row = rowbase + g * 4 + r;
            const size_t o  = ((size_t)wave * NN  + row) * 16 + n15;
            const size_t oq = ((size_t)wave * NNS + row) * 16 + n15;
            Kq[o]   = f2bf(__builtin_amdgcn_exp2f(fmaf(acc[0][r], -L2E, nbk)));
            QVq[oq] = pack_bf16x2(__builtin_amdgcn_exp2f(fmaf(acc[1][r], -L2E, nbq)),
                                  acc[2][r] + bvc);
            Hq[o]   = f2bf(acc[3][r] + bsc);
        }
    }
}

// ---------------------------------------------------------------------------
// Fused prep: deg histogram (blocks 0..3124) + W-fragment split (blocks
// 3125..3164) + QVq sentinel-row zeroing. Independent work, one launch.
// ---------------------------------------------------------------------------
__global__ __launch_bounds__(256) void prep_kernel(
    const int* __restrict__ ei, int* __restrict__ deg,
    const float* __restrict__ Wk, const float* __restrict__ Wq,
    const float* __restrict__ Wv, const float* __restrict__ Ws,
    bf16x8* __restrict__ whbuf, bf16x8* __restrict__ wlbuf,
    unsigned int* __restrict__ QVq)
{
    const int bid = blockIdx.x;
    if (bid < DEG_BLOCKS) {
        const int e = bid * 256 + threadIdx.x;
        if (e < NE) atomicAdd(&deg[ei[NE + e]], 1);
        return;
    }
    if (bid == DEG_BLOCKS && threadIdx.x < 64) {
        const int q = threadIdx.x >> 4, c = threadIdx.x & 15;
        QVq[((size_t)q * NNS + NN) * 16 + c] = 0u;   // sentinel row: e^-q=0, v=0
    }
    const int t = (bid - DEG_BLOCKS) * 256 + threadIdx.x;
    if (t >= NL * 2048) return;
    const int lane = t & 63;
    const int w    = (t >> 6) & 3;
    const int c    = (t >> 8) & 1;
    const int m    = (t >> 9) & 3;
    const int l    = t >> 11;

    const float* Wm4[4] = {Wk, Wq, Wv, Ws};
    const float* W = Wm4[m] + l * 4096;
    const int col = w * 16 + (lane & 15);
    const int g   = lane >> 4;

    bf16x8 h, lo;
#pragma unroll
    for (int j = 0; j < 8; j++) {
        const int k = g * 8 + j + 32 * c;
        short hs, ls;
        split_bf16(W[k * DD + col], hs, ls);
        h[j] = hs; lo[j] = ls;
    }
    whbuf[t] = h;
    wlbuf[t] = lo;
}

// ---------------------------------------------------------------------------
// Scans over PADDED degrees (multiple of 8).
// ---------------------------------------------------------------------------
__global__ __launch_bounds__(256) void scan_partial_kernel(
    const int* __restrict__ deg, int* __restrict__ psums)
{
    __shared__ int ls[256];
    const int i = blockIdx.x * 256 + threadIdx.x;
    ls[threadIdx.x] = (i < NN) ? PADDEG(deg[i]) : 0;
    __syncthreads();
    for (int off = 128; off > 0; off >>= 1) {
        if (threadIdx.x < off) ls[threadIdx.x] += ls[threadIdx.x + off];
        __syncthreads();
    }
    if (threadIdx.x == 0) psums[blockIdx.x] = ls[0];
}

// Wave-parallel exclusive scan over NCHUNK partials. 64 lanes x 4 chunks.
__global__ __launch_bounds__(64) void scan_offsets_kernel(
    int* __restrict__ psums, int* __restrict__ rowst)
{
    const int lane = threadIdx.x;
    const int base = lane * 4;
    int v[4];
    int s = 0;
#pragma unroll
    for (int j = 0; j < 4; j++) {
        v[j] = (base + j < NCHUNK) ? psums[base + j] : 0;
        s += v[j];
    }
    int incl = s;
    for (int off = 1; off < 64; off <<= 1) {
        const int t = __shfl_up(incl, off);
        if (lane >= off) incl += t;
    }
    const int total = __shfl(incl, 63);
    int run = incl - s;   // exclusive
#pragma unroll
    for (int j = 0; j < 4; j++) {
        if (base + j < NCHUNK) psums[base + j] = run;
        run += v[j];
    }
    if (lane == 0) rowst[NN] = total;  // padded edge total
}

__global__ __launch_bounds__(256) void scan_final_kernel(
    const int* __restrict__ deg, const int* __restrict__ psums,
    int* __restrict__ rowst, int* __restrict__ cursor)
{
    __shared__ int ls[256];
    const int i = blockIdx.x * 256 + threadIdx.x;
    const int x = (i < NN) ? PADDEG(deg[i]) : 0;
    ls[threadIdx.x] = x;
    __syncthreads();
    for (int off = 1; off < 256; off <<= 1) {
        int v = (threadIdx.x >= off) ? ls[threadIdx.x - off] : 0;
        __syncthreads();
        ls[threadIdx.x] += v;
        __syncthreads();
    }
    if (i < NN) {
        const int excl = psums[blockIdx.x] + ls[threadIdx.x] - x;
        rowst[i]  = excl;
        cursor[i] = excl;
    }
}

// ---------------------------------------------------------------------------
// Fused gemm0 + RANGE-PARTITIONED CSR fill + sentinel pad (R4-proven).
// ---------------------------------------------------------------------------
__global__ __launch_bounds__(256) void gfp_kernel(
    const float* __restrict__ X,
    const bf16x8* __restrict__ whbuf, const bf16x8* __restrict__ wlbuf,
    const float* __restrict__ bk, const float* __restrict__ bq,
    const float* __restrict__ bv, const float* __restrict__ bs,
    unsigned short* __restrict__ Kq, unsigned int* __restrict__ QVq,
    unsigned short* __restrict__ Hq,
    const int* __restrict__ ei, int* __restrict__ cursor,
    const int* __restrict__ rowst, const int* __restrict__ deg,
    unsigned short* __restrict__ csr16)
{
    const int bid = blockIdx.x;
    if (bid < GEMM_BLOCKS) {
        gemm_body<1>(X, whbuf, wlbuf, bk, bq, bv, bs,
                     nullptr, nullptr, nullptr, Kq, QVq, Hq, bid);
        return;
    }
    if (bid < GEMM_BLOCKS + FILLP_BLOCKS) {
        const int fid = bid - GEMM_BLOCKS;
        const int r   = bid & 7;            // dst-range == XCD (heuristic)
        const int o   = fid >> 3;           // edge chunk ordinal
        const int lo  = r * NRANGE;
        const int hi  = lo + NRANGE;
        const int e0  = o * FCHK;
        const int e1  = min(e0 + FCHK, NE);
        for (int e = e0 + threadIdx.x; e < e1; e += 256) {
            const int dst = ei[NE + e];
            if (dst >= lo && dst < hi) {
                const int src = ei[e];      // < 50000 < 65536 -> u16 exact
                csr16[atomicAdd(&cursor[dst], 1)] = (unsigned short)src;
            }
        }
        return;
    }
    const int n = (bid - GEMM_BLOCKS - FILLP_BLOCKS) * 256 + threadIdx.x;
    if (n >= NN) return;
    const int end = rowst[n + 1];
    for (int i = rowst[n] + deg[n]; i < end; i++) csr16[i] = (unsigned short)NN;
}

// ---------------------------------------------------------------------------
// gemm for layers 1..4 (bf16 input, prev-layer BN folded from replicated
// stats).
// ---------------------------------------------------------------------------
__global__ __launch_bounds__(256) void gemm4_mfma(
    const void* __restrict__ HinV,
    const bf16x8* __restrict__ whbuf, const bf16x8* __restrict__ wlbuf,
    const float* __restrict__ bk, const float* __restrict__ bq,
    const float* __restrict__ bv, const float* __restrict__ bs,
    const float* __restrict__ prevStats,
    const float* __restrict__ prevGamma, const float* __restrict__ prevBeta,
    unsigned short* __restrict__ Kq, unsigned int* __restrict__ QVq,
    unsigned short* __restrict__ Hq)
{
    gemm_body<0>(HinV, whbuf, wlbuf, bk, bq, bv, bs,
                 prevStats, prevGamma, prevBeta, Kq, QVq, Hq, blockIdx.x);
}

// ---------------------------------------------------------------------------
// Column-quarter XCD-partitioned gather — R4 body + replicated stats
// atomics (R8-proven, 55 us / 518 total).
// ---------------------------------------------------------------------------
#define GATHER_BLOCKS (8 * 782)   // 6256
__global__ __launch_bounds__(256) void gather_kernel(
    const int* __restrict__ rowst, const unsigned short* __restrict__ csr16,
    const unsigned short* __restrict__ Kq, const unsigned int* __restrict__ QVq,
    unsigned short* Hq, float* __restrict__ stats)
{
    const int tid  = threadIdx.x;
    const int wv   = tid >> 6;
    const int lane = tid & 63;
    const int eoff = lane >> 3;     // edge slot 0..7
    const int cp   = lane & 7;      // column pair (cols 2cp, 2cp+1)

    const int j       = blockIdx.x;
    const int xcd     = j & 7;
    const int quarter = xcd >> 1;
    const int half    = xcd & 1;
    const int nodebase = ((j >> 3) * 2 + half) * 32 + wv * 8;

    const unsigned* Kq32 = (const unsigned*)(Kq + (size_t)quarter * NN * 16);
    const uint2*    Qq2  = (const uint2*)(QVq + (size_t)quarter * NNS * 16);
    unsigned*       Hq32 = (unsigned*)(Hq + (size_t)quarter * NN * 16);

    float se = 0.f, s2e = 0.f, so = 0.f, s2o = 0.f;   // stats cols 2cp / 2cp+1

    int e00 = rowst[min(nodebase, NN)];   // carried: e00(t+1) = e11(t)

    for (int t = 0; t < 4; t++) {
        const int n0 = nodebase + 2 * t;   // even; n1 = n0+1 < NN when n0 < NN
        if (n0 >= NN) break;
        const int n1 = n0 + 1;
        const unsigned ho0 = (unsigned)(n0 * 8 + cp);
        const unsigned ho1 = (unsigned)(n1 * 8 + cp);
        unsigned h0p = 0u, h1p = 0u;
        if (eoff == 0) {                   // exec-masked prefetch of skip term
            h0p = Hq32[ho0];
            h1p = Hq32[ho1];
        }
        const unsigned k0p = Kq32[ho0];    // packed e^-k
        const unsigned k1p = Kq32[ho1];
        const float ek00 = bf2f((unsigned short)(k0p & 0xFFFFu));
        const float ek01 = bf2f((unsigned short)(k0p >> 16));
        const float ek10 = bf2f((unsigned short)(k1p & 0xFFFFu));
        const float ek11 = bf2f((unsigned short)(k1p >> 16));
        const int e01 = rowst[n1], e11 = rowst[n1 + 1];
        int nd0 = (e01 - e00) >> 3;        // padded slot counts
        int nd1 = (e11 - e01) >> 3;
        int ndm = min(nd0, nd1);
        nd0 -= ndm; nd1 -= ndm;
        int b0 = e00, b1 = e01;            // base edge indices (even)
        e00 = e11;                         // carry for next t
        float a00 = 0.f, a01 = 0.f, a10 = 0.f, a11 = 0.f;

        // dual-node main loop: 16 edges/node per iter, 2 u32 csr + 4 uint2
        // QVq loads in flight, 4 rcp per 8 gates.
        while (ndm >= 2) {
            const unsigned s0 = *(const unsigned*)(csr16 + b0 + 2 * eoff);
            const unsigned s1 = *(const unsigned*)(csr16 + b1 + 2 * eoff);
            const uint2 p0a = Qq2[(s0 & 0xFFFFu) * 8u + cp];
            const uint2 p0b = Qq2[(s0 >> 16) * 8u + cp];
            const uint2 p1a = Qq2[(s1 & 0xFFFFu) * 8u + cp];
            const uint2 p1b = Qq2[(s1 >> 16) * 8u + cp];
            GPAIR(ek00, p0a.x, p0b.x, a00);
            GPAIR(ek01, p0a.y, p0b.y, a01);
            GPAIR(ek10, p1a.x, p1b.x, a10);
            GPAIR(ek11, p1a.y, p1b.y, a11);
            b0 += 16; b1 += 16; ndm -= 2;
        }
        if (ndm) {   // one joint slot left (u16 per lane)
            const int s0 = csr16[b0 + eoff];
            const int s1 = csr16[b1 + eoff];
            const uint2 p0 = Qq2[(unsigned)(s0 * 8 + cp)];
            const uint2 p1 = Qq2[(unsigned)(s1 * 8 + cp)];
            GCOLS(ek00, ek01, p0, a00, a01);
            GCOLS(ek10, ek11, p1, a10, a11);
            b0 += 8; b1 += 8;
        }
        while (nd0 >= 2) {   // node-0 surplus, 16-edge steps
            const unsigned s0 = *(const unsigned*)(csr16 + b0 + 2 * eoff);
            const uint2 p0a = Qq2[(s0 & 0xFFFFu) * 8u + cp];
            const uint2 p0b = Qq2[(s0 >> 16) * 8u + cp];
            GPAIR(ek00, p0a.x, p0b.x, a00);
            GPAIR(ek01, p0a.y, p0b.y, a01);
            b0 += 16; nd0 -= 2;
        }
        if (nd0) {
            const int s0 = csr16[b0 + eoff];
            const uint2 p0 = Qq2[(unsigned)(s0 * 8 + cp)];
            GCOLS(ek00, ek01, p0, a00, a01);
        }
        while (nd1 >= 2) {   // node-1 surplus, 16-edge steps
            const unsigned s1 = *(const unsigned*)(csr16 + b1 + 2 * eoff);
            const uint2 p1a = Qq2[(s1 & 0xFFFFu) * 8u + cp];
            const uint2 p1b = Qq2[(s1 >> 16) * 8u + cp];
            GPAIR(ek10, p1a.x, p1b.x, a10);
            GPAIR(ek11, p1a.y, p1b.y, a11);
            b1 += 16; nd1 -= 2;
        }
        if (nd1) {
            const int s1 = csr16[b1 + eoff];
            const uint2 p1 = Qq2[(unsigned)(s1 * 8 + cp)];
            GCOLS(ek10, ek11, p1, a10, a11);
        }

        // combine edge slots: lanes cp, cp+8, ..., cp+56 share columns
        a00 += __shfl_xor(a00, 8);  a00 += __shfl_xor(a00, 16); a00 += __shfl_xor(a00, 32);
        a01 += __shfl_xor(a01, 8);  a01 += __shfl_xor(a01, 16); a01 += __shfl_xor(a01, 32);
        a10 += __shfl_xor(a10, 8);  a10 += __shfl_xor(a10, 16); a10 += __shfl_xor(a10, 32);
        a11 += __shfl_xor(a11, 8);  a11 += __shfl_xor(a11, 16); a11 += __shfl_xor(a11, 32);

        if (eoff == 0) {
            const float o00 = fmaxf(bf2f((unsigned short)(h0p & 0xFFFFu)) + a00, 0.f);
            const float o01 = fmaxf(bf2f((unsigned short)(h0p >> 16))     + a01, 0.f);
            const float o10 = fmaxf(bf2f((unsigned short)(h1p & 0xFFFFu)) + a10, 0.f);
            const float o11 = fmaxf(bf2f((unsigned short)(h1p >> 16))     + a11, 0.f);
            const unsigned short b00 = f2bf(o00), b01 = f2bf(o01);
            const unsigned short b10 = f2bf(o10), b11 = f2bf(o11);
            Hq32[ho0] = ((unsigned)b01 << 16) | b00;
            Hq32[ho1] = ((unsigned)b11 << 16) | b10;
            const float r00 = bf2f(b00), r01 = bf2f(b01);
            const float r10 = bf2f(b10), r11 = bf2f(b11);
            se  += r00 + r10;  s2e += r00 * r00 + r10 * r10;
            so  += r01 + r11;  s2o += r01 * r01 + r11 * r11;
        }
    }

    __shared__ float ls[64], ls2[64];   // 4 waves x 16 cols
    if (eoff == 0) {
        ls[wv * 16 + 2 * cp]      = se;  ls2[wv * 16 + 2 * cp]      = s2e;
        ls[wv * 16 + 2 * cp + 1]  = so;  ls2[wv * 16 + 2 * cp + 1]  = s2o;
    }
    __syncthreads();
    if (tid < 16) {
        const int rep = (j >> 3) & (SREP - 1);   // stats replica
        const float a = ls[tid] + ls[16 + tid] + ls[32 + tid] + ls[48 + tid];
        const float b = ls2[tid] + ls2[16 + tid] + ls2[32 + tid] + ls2[48 + tid];
        atomicAdd(&stats[rep * 128 + quarter * 16 + tid], a);
        atomicAdd(&stats[rep * 128 + 64 + quarter * 16 + tid], b);
    }
}

// ---------------------------------------------------------------------------
// Pooled segment-sum over quarter-major bf16 H (batch sorted). u32 loads:
// 32 threads per 64-row chunk, each thread owns 2 adjacent cols; 8 chunks
// per 256-thread block.
// ---------------------------------------------------------------------------
#define POOL_ROWS 64
__global__ __launch_bounds__(256) void pool_kernel(
    const unsigned short* __restrict__ Hq, const int* __restrict__ batch,
    float* __restrict__ psum, float* __restrict__ pcnt)
{
    const int sub = threadIdx.x >> 5;   // chunk 0..7
    const int c   = threadIdx.x & 31;   // col-pair id
    const int q   = c >> 3;             // quarter
    const int p   = c & 7;              // pair within quarter (cols 2p, 2p+1)
    const int r0 = (blockIdx.x * 8 + sub) * POOL_ROWS;
    if (r0 >= NN) return;
    const int r1 = min(r0 + POOL_ROWS, NN);
    const unsigned* Hqq = (const unsigned*)(Hq + (size_t)q * NN * 16);
    const int col0 = q * 16 + 2 * p;

    int cur = batch[r0];
    float acc0 = 0.f, acc1 = 0.f, cnt = 0.f;
    for (int r = r0; r < r1; r++) {
        const int g = batch[r];
        if (g != cur) {
            atomicAdd(&psum[cur * DD + col0], acc0);
            atomicAdd(&psum[cur * DD + col0 + 1], acc1);
            if (c == 0) atomicAdd(&pcnt[cur], cnt);
            acc0 = 0.f; acc1 = 0.f; cnt = 0.f; cur = g;
        }
        const unsigned hv = Hqq[(size_t)r * 8 + p];
        acc0 += bf2f((unsigned short)(hv & 0xFFFFu));
        acc1 += bf2f((unsigned short)(hv >> 16));
        cnt += 1.f;
    }
    atomicAdd(&psum[cur * DD + col0], acc0);
    atomicAdd(&psum[cur * DD + col0 + 1], acc1);
    if (c == 0) atomicAdd(&pcnt[cur], cnt);
}

// ---------------------------------------------------------------------------
// Final head, PARALLELIZED: one block (one wave) per graph — 256 blocks vs
// the old 1-block/256-thread version that ran 70 us at 0.04% occupancy
// (scratch-spilled p[64]+logits[10], ~311K latency-bound loads on 1 CU).
// Thread d owns column d: BN-fold scalar (no arrays); per-class partials
// reduced across the wave via shfl_xor; softmax in-register; lane c<NC
// writes out[g*NC+c] via unrolled select (static indexing).
// ---------------------------------------------------------------------------
__global__ __launch_bounds__(64) void final_kernel(
    const float* __restrict__ psum, const float* __restrict__ pcnt,
    const float* __restrict__ stats,
    const float* __restrict__ gamma, const float* __restrict__ beta,
    const float* __restrict__ Wlin, const float* __restrict__ blin,
    float* __restrict__ out)
{
    const int g = blockIdx.x;        // graph
    const int d = threadIdx.x;       // column 0..63

    float s1 = 0.f, s2 = 0.f;
#pragma unroll
    for (int r = 0; r < SREP; r++) {
        s1 += stats[r * 128 + d];
        s2 += stats[r * 128 + 64 + d];
    }
    const float invN = 1.0f / (float)NN;
    const float mean = s1 * invN;
    const float var  = s2 * invN - mean * mean;
    const float inv  = rsqrtf(var + BN_EPS);
    const float a = inv * gamma[d];
    const float b = beta[d] - mean * a;
    const float invc = 1.0f / fmaxf(pcnt[g], 1.0f);
    const float pd = fmaf(psum[g * DD + d] * invc, a, b);

    float logits[NC];
#pragma unroll
    for (int c = 0; c < NC; c++) {
        float part = pd * Wlin[d * NC + c];
        part += __shfl_xor(part, 1);  part += __shfl_xor(part, 2);
        part += __shfl_xor(part, 4);  part += __shfl_xor(part, 8);
        part += __shfl_xor(part, 16); part += __shfl_xor(part, 32);
        logits[c] = part + blin[c];
    }
    float m = -1e30f;
#pragma unroll
    for (int c = 0; c < NC; c++) m = fmaxf(m, logits[c]);
    float sum = 0.f;
#pragma unroll
    for (int c = 0; c < NC; c++) {
        logits[c] = __expf(logits[c] - m);
        sum += logits[c];
    }
    const float invs = 1.f / sum;
    if (d < NC) {
        float mine = logits[0];
#pragma unroll
        for (int c = 1; c < NC; c++) mine = (d == c) ? logits[c] : mine;
        out[g * NC + d] = mine * invs;
    }
}

// ---------------------------------------------------------------------------
extern "C" void kernel_launch(void* const* d_in, const int* in_sizes, int n_in,
                              void* d_out, int out_size, void* d_ws, size_t ws_size,
                              hipStream_t stream)
{
    const float* X     = (const float*)d_in[0];
    const int*   ei    = (const int*)d_in[1];
    const int*   batch = (const int*)d_in[2];
    const float* Wk    = (const float*)d_in[3];
    const float* Wq    = (const float*)d_in[4];
    const float* Wv    = (const float*)d_in[5];
    const float* Ws    = (const float*)d_in[6];
    const float* bk    = (const float*)d_in[7];
    const float* bq    = (const float*)d_in[8];
    const float* bv    = (const float*)d_in[9];
    const float* bconv = (const float*)d_in[10];
    const float* gamma = (const float*)d_in[11];
    const float* beta  = (const float*)d_in[12];
    const float* Wlin  = (const float*)d_in[13];
    const float* blin  = (const float*)d_in[14];
    float* out = (float*)d_out;

    const size_t M  = (size_t)NN * DD;        // == 4 * NN * 16
    const size_t MQ = (size_t)4 * NNS * 16;   // QVq uints (padded stride)
    unsigned short* Kq  = (unsigned short*)d_ws;      // M bf16 (e^-k), quarter-major
    unsigned int*   QVq = (unsigned int*)(Kq + M);    // MQ packed (e^-q|v), stride NNS
    unsigned short* H0q = (unsigned short*)(QVq + MQ);// M bf16, quarter-major
    unsigned short* H1q = H0q + M;                    // M bf16
    // --- contiguous zero-init region ---
    int*   deg   = (int*)(H1q + M);                   // NN
    float* psum  = (float*)(deg + NN);                // NG*DD
    float* pcnt  = psum + (size_t)NG * DD;            // NG
    float* stats = pcnt + NG;                         // NL*SSTR (4-replica)
    // --- end zero region ---
    int* rowst  = (int*)(stats + NL * SSTR);          // NN+1
    int* cursor = rowst + NN + 1;                     // NN
    int* psums  = cursor + NN;                        // 256
    unsigned short* csr16 = (unsigned short*)(psums + 256);  // NE + 8*NN u16 (padded)
    bf16x8* whbuf = (bf16x8*)(csr16 + NE + 8 * NN);   // NL*2048 frags
    bf16x8* wlbuf = whbuf + NL * 2048;

    const size_t zero_bytes = (size_t)(NN + NG * DD + NG + NL * SSTR) * 4;
    hipMemsetAsync(deg, 0, zero_bytes, stream);

    // ---- fused deg histogram + W fragment prep + sentinel zeroing ----
    prep_kernel<<<DEG_BLOCKS + WPREP_BLOCKS, 256, 0, stream>>>(
        ei, deg, Wk, Wq, Wv, Ws, whbuf, wlbuf, QVq);

    // ---- scans over padded degrees ----
    scan_partial_kernel<<<NCHUNK, 256, 0, stream>>>(deg, psums);
    scan_offsets_kernel<<<1, 64, 0, stream>>>(psums, rowst);
    scan_final_kernel<<<NCHUNK, 256, 0, stream>>>(deg, psums, rowst, cursor);

    // ---- fused layer-0 gemm + range-partitioned CSR fill + sentinel pad ----
    gfp_kernel<<<GEMM_BLOCKS + FILLP_BLOCKS + PAD_BLOCKS, 256, 0, stream>>>(
        X, whbuf, wlbuf, bk, bq, bv, bconv,
        Kq, QVq, H0q, ei, cursor, rowst, deg, csr16);

    // ---- layers ----
    gather_kernel<<<GATHER_BLOCKS, 256, 0, stream>>>(
        rowst, csr16, Kq, QVq, H0q, stats);
    const void* hin = (const void*)H0q;
    for (int l = 1; l < NL; l++) {
        unsigned short* hout = (l & 1) ? H1q : H0q;
        gemm4_mfma<<<GEMM_BLOCKS, 256, 0, stream>>>(
            hin, whbuf + l * 2048, wlbuf + l * 2048,
            bk + l * 64, bq + l * 64, bv + l * 64, bconv + l * 64,
            stats + (l - 1) * SSTR, gamma + (l - 1) * 64, beta + (l - 1) * 64,
            Kq, QVq, hout);
        gather_kernel<<<GATHER_BLOCKS, 256, 0, stream>>>(
            rowst, csr16, Kq, QVq, hout, stats + l * SSTR);
        hin = (const void*)hout;
    }

    pool_kernel<<<(NN + 8 * POOL_ROWS - 1) / (8 * POOL_ROWS), 256, 0, stream>>>(
        (const unsigned short*)hin, batch, psum, pcnt);
    final_kernel<<<NG, 64, 0, stream>>>(
        psum, pcnt, stats + 4 * SSTR, gamma + 4 * 64, beta + 4 * 64, Wlin, blin, out);
}

// Round 10
// 453.879 us; speedup vs baseline: 1.2160x; 1.0032x over previous
//
#include <hip/hip_runtime.h>

#define NN 50000
#define NE 800000
#define DD 64
#define NL 5
#define NG 256
#define NC 10
#define BN_EPS 1e-5f
#define NCHUNK ((NN + 255) / 256)   // 196
#define GROWS 128                    // rows per gemm block (R4-proven)
#define GT (GROWS / 16)              // 16-row tiles per block
#define SAW 68                       // staged-A row stride (uints)
#define GEMM_BLOCKS ((NN + GROWS - 1) / GROWS)   // 391
#define NNS (NN + 8)                 // QVq per-quarter row stride (sentinel at row NN)
#define PADDEG(d) (((d) + 7) & ~7)   // csr segment padded to multiple of 8
#define DEG_BLOCKS ((NE + 255) / 256)        // 3125
#define WPREP_BLOCKS ((NL * 2048 + 255) / 256)  // 40
#define FCHK 2048                            // edges per fill chunk
#define FCHUNKS ((NE + FCHK - 1) / FCHK)     // 391
#define FILLP_BLOCKS (8 * FCHUNKS)           // 3128 (8 dst-ranges x chunks)
#define NRANGE (NN / 8)                      // 6250 nodes per dst-range
#define PAD_BLOCKS NCHUNK                    // 196
#define SREP 4                               // stats replicas (atomic contention /4)
#define SSTR (SREP * 128)                    // per-layer stats stride (512 floats)
#define POOL_ROWS 64
#define POOL_SUBS 4                          // 196 blocks (was 98 — underfilled chip)
#define L2E 1.4426950408889634f              // log2(e)

typedef __attribute__((ext_vector_type(8))) short bf16x8;
typedef __attribute__((ext_vector_type(4))) float f32x4;

__device__ inline float bf2f(unsigned short u) {
    return __uint_as_float((unsigned)u << 16);
}
__device__ inline unsigned short f2bf(float x) {   // RNE
    unsigned u = __float_as_uint(x);
    u += 0x7FFFu + ((u >> 16) & 1u);
    return (unsigned short)(u >> 16);
}

// Pack two floats as bf16 (RNE) into one uint: low16 = a, high16 = b.
__device__ inline unsigned int pack_bf16x2(float a, float b) {
    unsigned int ua = __float_as_uint(a);
    unsigned int ub = __float_as_uint(b);
    ua += 0x7FFFu + ((ua >> 16) & 1u);
    ub += 0x7FFFu + ((ub >> 16) & 1u);
    return (ub & 0xFFFF0000u) | (ua >> 16);
}

// Split fp32 into bf16 hi (RTZ) + bf16 lo (residual). hi+lo ~ x to ~2^-17.
__device__ inline void split_bf16(float x, short& h, short& l) {
    const unsigned u  = __float_as_uint(x);
    const unsigned hb = u & 0xFFFF0000u;
    h = (short)(hb >> 16);
    const float lo = x - __uint_as_float(hb);
    l = (short)(__float_as_uint(lo) >> 16);
}

// packed (e^-q | v) accessors: low16 = e^-q, high16 = v.
__device__ inline float p_eq(unsigned p) { return __uint_as_float(p << 16); }
__device__ inline float p_v(unsigned p)  { return __uint_as_float(p & 0xFFFF0000u); }

// Two gates sharing one ek (batched reciprocal, 1 rcp for 2 gates):
// v1/t1 + v2/t2 = (v1*t2 + v2*t1) * rcp(t1*t2).  [numerics proven in R2]
#define GPAIR(ek, pa, pb, acc) { \
    const float t1_ = fmaf(ek, p_eq(pa), 1.f); \
    const float t2_ = fmaf(ek, p_eq(pb), 1.f); \
    const float R_  = __builtin_amdgcn_rcpf(t1_ * t2_); \
    acc = fmaf(fmaf(p_v(pb), t1_, p_v(pa) * t2_), R_, acc); }

// Two gates with different ek (one uint2's two cols): inverse recovery,
// R=rcp(t1*t2); 1/t1=R*t2; 1/t2=R*t1.  [numerics proven in R2]
#define GCOLS(ekx, eky, p, accx, accy) { \
    const float t1_ = fmaf(ekx, p_eq(p.x), 1.f); \
    const float t2_ = fmaf(eky, p_eq(p.y), 1.f); \
    const float R_  = __builtin_amdgcn_rcpf(t1_ * t2_); \
    accx = fmaf(p_v(p.x), R_ * t2_, accx); \
    accy = fmaf(p_v(p.y), R_ * t1_, accy); }

// ---------------------------------------------------------------------------
// Shared GEMM body (MFMA, inline prev-layer BN for bf16 path, QUARTER-MAJOR
// outputs): Kq stores e^-k; QVq packs (e^-q | v); Hq stores skip+bias.
// exp via raw v_exp_f32: e^-(acc+b) = 2^fma(acc,-log2e, -b*log2e).
// prevStats is 4-way replicated (SREP x 128) — summed here.
// W-FRAGMENT LOADS HOISTED to the top: at ~1.5 waves/SIMD there is no other
// wave to hide the 256B/lane L2 reads behind — issuing them before the
// staging loop overlaps them with the staging HBM loads.
// F32=1: layer-0 path (fp32 X input, no BN fold).
// ---------------------------------------------------------------------------
template<int F32>
__device__ __forceinline__ void gemm_body(
    const void* __restrict__ HinV,
    const bf16x8* __restrict__ whbuf, const bf16x8* __restrict__ wlbuf,
    const float* __restrict__ bk, const float* __restrict__ bq,
    const float* __restrict__ bv, const float* __restrict__ bs,
    const float* __restrict__ prevStats,
    const float* __restrict__ prevGamma, const float* __restrict__ prevBeta,
    unsigned short* __restrict__ Kq, unsigned int* __restrict__ QVq,
    unsigned short* __restrict__ Hq, const int gb)
{
    __shared__ unsigned int sA[GROWS * SAW];   // packed split-bf16 A
    __shared__ float sAB[128];                 // a[64], b[64]
    const int tid = threadIdx.x;

    const int wave = tid >> 6;    // column tile == quarter
    const int lane = tid & 63;
    const int n15  = lane & 15;
    const int g    = lane >> 4;
    const int col  = wave * 16 + n15;

    // ---- hoisted W-fragment + bias loads (independent of staging) ----
    bf16x8 wh[4][2], wl[4][2];
    {
        const int base = wave * 64 + lane;
#pragma unroll
        for (int m = 0; m < 4; m++)
#pragma unroll
            for (int c = 0; c < 2; c++) {
                const int idx = m * 512 + c * 256 + base;
                wh[m][c] = whbuf[idx];
                wl[m][c] = wlbuf[idx];
            }
    }
    const float nbk = -bk[col] * L2E;   // folded: 2^(acc*-L2E + nbk) = e^-(acc+bk)
    const float nbq = -bq[col] * L2E;
    const float bvc = bv[col], bsc = bs[col];

    if (!F32) {
        if (tid < 64) {
            float s1 = 0.f, s2 = 0.f;
#pragma unroll
            for (int r = 0; r < SREP; r++) {
                s1 += prevStats[r * 128 + tid];
                s2 += prevStats[r * 128 + 64 + tid];
            }
            const float invN = 1.0f / (float)NN;
            const float mean = s1 * invN;
            const float var  = s2 * invN - mean * mean;
            const float inv  = rsqrtf(var + BN_EPS);
            const float a = inv * prevGamma[tid];
            sAB[tid]      = a;
            sAB[64 + tid] = prevBeta[tid] - mean * a;
        }
        __syncthreads();
    }

    const int row0 = gb * GROWS;
    if (F32) {
        const float* X = (const float*)HinV;
        for (int i = tid; i < GROWS * 16; i += 256) {
            const int row = i >> 4;
            const int k4  = (i & 15) * 4;
            float4 x = make_float4(0.f, 0.f, 0.f, 0.f);
            if (row0 + row < NN)
                x = *(const float4*)(X + (size_t)(row0 + row) * DD + k4);
            const float xs[4] = {x.x, x.y, x.z, x.w};
            unsigned int* dst = &sA[row * SAW + k4];
#pragma unroll
            for (int j = 0; j < 4; j++) {
                short hs, ls;
                split_bf16(xs[j], hs, ls);
                dst[j] = ((unsigned int)(unsigned short)hs << 16) | (unsigned short)ls;
            }
        }
    } else {
        const unsigned short* Hin = (const unsigned short*)HinV;
        for (int i = tid; i < GROWS * 8; i += 256) {
            const int row = i >> 3;
            const int cb  = (i & 7) * 8;   // col base: 0,8,..,56
            const int q   = cb >> 4;
            const int o16 = cb & 15;       // 0 or 8
            uint4 v = make_uint4(0u, 0u, 0u, 0u);
            if (row0 + row < NN)
                v = *(const uint4*)&Hin[((size_t)q * NN + row0 + row) * 16 + o16];
            const unsigned ws[4] = {v.x, v.y, v.z, v.w};
            unsigned int* dst = &sA[row * SAW + cb];
#pragma unroll
            for (int j = 0; j < 4; j++) {
                const float x0 = bf2f((unsigned short)(ws[j] & 0xFFFFu));
                const float x1 = bf2f((unsigned short)(ws[j] >> 16));
                const int c0 = cb + 2 * j, c1 = cb + 2 * j + 1;
                short hs, ls;
                split_bf16(fmaf(x0, sAB[c0], sAB[64 + c0]), hs, ls);
                dst[2 * j] = ((unsigned int)(unsigned short)hs << 16) | (unsigned short)ls;
                split_bf16(fmaf(x1, sAB[c1], sAB[64 + c1]), hs, ls);
                dst[2 * j + 1] = ((unsigned int)(unsigned short)hs << 16) | (unsigned short)ls;
            }
        }
    }

    __syncthreads();

#pragma unroll 1
    for (int t = 0; t < GT; t++) {
        const int rowbase = row0 + t * 16;
        if (rowbase >= NN) break;   // NN % 16 == 0

        bf16x8 ah[2], al[2];
#pragma unroll
        for (int c = 0; c < 2; c++) {
            const uint4 u0 = *(const uint4*)&sA[(t * 16 + n15) * SAW + g * 8 + 32 * c];
            const uint4 u1 = *(const uint4*)&sA[(t * 16 + n15) * SAW + g * 8 + 32 * c + 4];
            const unsigned int us[8] = {u0.x, u0.y, u0.z, u0.w, u1.x, u1.y, u1.z, u1.w};
            bf16x8 h, l;
#pragma unroll
            for (int j = 0; j < 8; j++) {
                h[j] = (short)(us[j] >> 16);
                l[j] = (short)(us[j] & 0xFFFFu);
            }
            ah[c] = h; al[c] = l;
        }

        f32x4 acc[4];
#pragma unroll
        for (int m = 0; m < 4; m++) acc[m] = (f32x4){0.f, 0.f, 0.f, 0.f};

#pragma unroll
        for (int c = 0; c < 2; c++) {
#pragma unroll
            for (int m = 0; m < 4; m++) {
                acc[m] = __builtin_amdgcn_mfma_f32_16x16x32_bf16(ah[c], wh[m][c], acc[m], 0, 0, 0);
                acc[m] = __builtin_amdgcn_mfma_f32_16x16x32_bf16(al[c], wh[m][c], acc[m], 0, 0, 0);
                acc[m] = __builtin_amdgcn_mfma_f32_16x16x32_bf16(ah[c], wl[m][c], acc[m], 0, 0, 0);
            }
        }

#pragma unroll
        for (int r = 0; r < 4; r++) {
            const int row = rowbase + g * 4 + r;
            const size_t o  = ((size_t)wave * NN  + row) * 16 + n15;
            const size_t oq = ((size_t)wave * NNS + row) * 16 + n15;
            Kq[o]   = f2bf(__builtin_amdgcn_exp2f(fmaf(acc[0][r], -L2E, nbk)));
            QVq[oq] = pack_bf16x2(__builtin_amdgcn_exp2f(fmaf(acc[1][r], -L2E, nbq)),
                                  acc[2][r] + bvc);
            Hq[o]   = f2bf(acc[3][r] + bsc);
        }
    }
}

// ---------------------------------------------------------------------------
// Fused prep: deg histogram (blocks 0..3124) + W-fragment split (blocks
// 3125..3164) + QVq sentinel-row zeroing. Independent work, one launch.
// ---------------------------------------------------------------------------
__global__ __launch_bounds__(256) void prep_kernel(
    const int* __restrict__ ei, int* __restrict__ deg,
    const float* __restrict__ Wk, const float* __restrict__ Wq,
    const float* __restrict__ Wv, const float* __restrict__ Ws,
    bf16x8* __restrict__ whbuf, bf16x8* __restrict__ wlbuf,
    unsigned int* __restrict__ QVq)
{
    const int bid = blockIdx.x;
    if (bid < DEG_BLOCKS) {
        const int e = bid * 256 + threadIdx.x;
        if (e < NE) atomicAdd(&deg[ei[NE + e]], 1);
        return;
    }
    if (bid == DEG_BLOCKS && threadIdx.x < 64) {
        const int q = threadIdx.x >> 4, c = threadIdx.x & 15;
        QVq[((size_t)q * NNS + NN) * 16 + c] = 0u;   // sentinel row: e^-q=0, v=0
    }
    const int t = (bid - DEG_BLOCKS) * 256 + threadIdx.x;
    if (t >= NL * 2048) return;
    const int lane = t & 63;
    const int w    = (t >> 6) & 3;
    const int c    = (t >> 8) & 1;
    const int m    = (t >> 9) & 3;
    const int l    = t >> 11;

    const float* Wm4[4] = {Wk, Wq, Wv, Ws};
    const float* W = Wm4[m] + l * 4096;
    const int col = w * 16 + (lane & 15);
    const int g   = lane >> 4;

    bf16x8 h, lo;
#pragma unroll
    for (int j = 0; j < 8; j++) {
        const int k = g * 8 + j + 32 * c;
        short hs, ls;
        split_bf16(W[k * DD + col], hs, ls);
        h[j] = hs; lo[j] = ls;
    }
    whbuf[t] = h;
    wlbuf[t] = lo;
}

// ---------------------------------------------------------------------------
// Scans over PADDED degrees (multiple of 8). Two launches total:
// scan_partial publishes per-block sums; scan_final computes its own block
// prefix in-kernel (wave-0 sums psums[0..bid), L2-hot, ~trivial) — the old
// scan_offsets launch is eliminated.
// ---------------------------------------------------------------------------
__global__ __launch_bounds__(256) void scan_partial_kernel(
    const int* __restrict__ deg, int* __restrict__ psums)
{
    __shared__ int ls[256];
    const int i = blockIdx.x * 256 + threadIdx.x;
    ls[threadIdx.x] = (i < NN) ? PADDEG(deg[i]) : 0;
    __syncthreads();
    for (int off = 128; off > 0; off >>= 1) {
        if (threadIdx.x < off) ls[threadIdx.x] += ls[threadIdx.x + off];
        __syncthreads();
    }
    if (threadIdx.x == 0) psums[blockIdx.x] = ls[0];
}

__global__ __launch_bounds__(256) void scan_final_kernel(
    const int* __restrict__ deg, const int* __restrict__ psums,
    int* __restrict__ rowst, int* __restrict__ cursor)
{
    __shared__ int ls[256];
    __shared__ int sPref;
    const int i = blockIdx.x * 256 + threadIdx.x;
    const int x = (i < NN) ? PADDEG(deg[i]) : 0;
    ls[threadIdx.x] = x;
    __syncthreads();
    for (int off = 1; off < 256; off <<= 1) {
        int v = (threadIdx.x >= off) ? ls[threadIdx.x - off] : 0;
        __syncthreads();
        ls[threadIdx.x] += v;
        __syncthreads();
    }
    if (threadIdx.x < 64) {    // wave-0: block prefix over preceding psums
        int p = 0;
        for (int j = threadIdx.x; j < blockIdx.x; j += 64) p += psums[j];
        p += __shfl_xor(p, 1);  p += __shfl_xor(p, 2);  p += __shfl_xor(p, 4);
        p += __shfl_xor(p, 8);  p += __shfl_xor(p, 16); p += __shfl_xor(p, 32);
        if (threadIdx.x == 0) sPref = p;
    }
    __syncthreads();
    if (i < NN) {
        const int excl = sPref + ls[threadIdx.x] - x;
        rowst[i]  = excl;
        cursor[i] = excl;
    }
    if (blockIdx.x == NCHUNK - 1 && threadIdx.x == 255)
        rowst[NN] = sPref + ls[255];   // padded edge total
}

// ---------------------------------------------------------------------------
// Fused gemm0 + RANGE-PARTITIONED CSR fill + sentinel pad (R4-proven).
// ---------------------------------------------------------------------------
__global__ __launch_bounds__(256) void gfp_kernel(
    const float* __restrict__ X,
    const bf16x8* __restrict__ whbuf, const bf16x8* __restrict__ wlbuf,
    const float* __restrict__ bk, const float* __restrict__ bq,
    const float* __restrict__ bv, const float* __restrict__ bs,
    unsigned short* __restrict__ Kq, unsigned int* __restrict__ QVq,
    unsigned short* __restrict__ Hq,
    const int* __restrict__ ei, int* __restrict__ cursor,
    const int* __restrict__ rowst, const int* __restrict__ deg,
    unsigned short* __restrict__ csr16)
{
    const int bid = blockIdx.x;
    if (bid < GEMM_BLOCKS) {
        gemm_body<1>(X, whbuf, wlbuf, bk, bq, bv, bs,
                     nullptr, nullptr, nullptr, Kq, QVq, Hq, bid);
        return;
    }
    if (bid < GEMM_BLOCKS + FILLP_BLOCKS) {
        const int fid = bid - GEMM_BLOCKS;
        const int r   = bid & 7;            // dst-range == XCD (heuristic)
        const int o   = fid >> 3;           // edge chunk ordinal
        const int lo  = r * NRANGE;
        const int hi  = lo + NRANGE;
        const int e0  = o * FCHK;
        const int e1  = min(e0 + FCHK, NE);
        for (int e = e0 + threadIdx.x; e < e1; e += 256) {
            const int dst = ei[NE + e];
            if (dst >= lo && dst < hi) {
                const int src = ei[e];      // < 50000 < 65536 -> u16 exact
                csr16[atomicAdd(&cursor[dst], 1)] = (unsigned short)src;
            }
        }
        return;
    }
    const int n = (bid - GEMM_BLOCKS - FILLP_BLOCKS) * 256 + threadIdx.x;
    if (n >= NN) return;
    const int end = rowst[n + 1];
    for (int i = rowst[n] + deg[n]; i < end; i++) csr16[i] = (unsigned short)NN;
}

// ---------------------------------------------------------------------------
// gemm for layers 1..4 (bf16 input, prev-layer BN folded from replicated
// stats).
// ---------------------------------------------------------------------------
__global__ __launch_bounds__(256) void gemm4_mfma(
    const void* __restrict__ HinV,
    const bf16x8* __restrict__ whbuf, const bf16x8* __restrict__ wlbuf,
    const float* __restrict__ bk, const float* __restrict__ bq,
    const float* __restrict__ bv, const float* __restrict__ bs,
    const float* __restrict__ prevStats,
    const float* __restrict__ prevGamma, const float* __restrict__ prevBeta,
    unsigned short* __restrict__ Kq, unsigned int* __restrict__ QVq,
    unsigned short* __restrict__ Hq)
{
    gemm_body<0>(HinV, whbuf, wlbuf, bk, bq, bv, bs,
                 prevStats, prevGamma, prevBeta, Kq, QVq, Hq, blockIdx.x);
}

// ---------------------------------------------------------------------------
// Column-quarter XCD-partitioned gather — R4 body + replicated stats
// atomics (R8/R9-proven, ~45 us). FROZEN: three scheduling grafts (R2 full
// restructure, R5 readfirstlane, R6 csr prefetch) all regressed; only work
// removal has ever helped this kernel.
// ---------------------------------------------------------------------------
#define GATHER_BLOCKS (8 * 782)   // 6256
__global__ __launch_bounds__(256) void gather_kernel(
    const int* __restrict__ rowst, const unsigned short* __restrict__ csr16,
    const unsigned short* __restrict__ Kq, const unsigned int* __restrict__ QVq,
    unsigned short* Hq, float* __restrict__ stats)
{
    const int tid  = threadIdx.x;
    const int wv   = tid >> 6;
    const int lane = tid & 63;
    const int eoff = lane >> 3;     // edge slot 0..7
    const int cp   = lane & 7;      // column pair (cols 2cp, 2cp+1)

    const int j       = blockIdx.x;
    const int xcd     = j & 7;
    const int quarter = xcd >> 1;
    const int half    = xcd & 1;
    const int nodebase = ((j >> 3) * 2 + half) * 32 + wv * 8;

    const unsigned* Kq32 = (const unsigned*)(Kq + (size_t)quarter * NN * 16);
    const uint2*    Qq2  = (const uint2*)(QVq + (size_t)quarter * NNS * 16);
    unsigned*       Hq32 = (unsigned*)(Hq + (size_t)quarter * NN * 16);

    float se = 0.f, s2e = 0.f, so = 0.f, s2o = 0.f;   // stats cols 2cp / 2cp+1

    int e00 = rowst[min(nodebase, NN)];   // carried: e00(t+1) = e11(t)

    for (int t = 0; t < 4; t++) {
        const int n0 = nodebase + 2 * t;   // even; n1 = n0+1 < NN when n0 < NN
        if (n0 >= NN) break;
        const int n1 = n0 + 1;
        const unsigned ho0 = (unsigned)(n0 * 8 + cp);
        const unsigned ho1 = (unsigned)(n1 * 8 + cp);
        unsigned h0p = 0u, h1p = 0u;
        if (eoff == 0) {                   // exec-masked prefetch of skip term
            h0p = Hq32[ho0];
            h1p = Hq32[ho1];
        }
        const unsigned k0p = Kq32[ho0];    // packed e^-k
        const unsigned k1p = Kq32[ho1];
        const float ek00 = bf2f((unsigned short)(k0p & 0xFFFFu));
        const float ek01 = bf2f((unsigned short)(k0p >> 16));
        const float ek10 = bf2f((unsigned short)(k1p & 0xFFFFu));
        const float ek11 = bf2f((unsigned short)(k1p >> 16));
        const int e01 = rowst[n1], e11 = rowst[n1 + 1];
        int nd0 = (e01 - e00) >> 3;        // padded slot counts
        int nd1 = (e11 - e01) >> 3;
        int ndm = min(nd0, nd1);
        nd0 -= ndm; nd1 -= ndm;
        int b0 = e00, b1 = e01;            // base edge indices (even)
        e00 = e11;                         // carry for next t
        float a00 = 0.f, a01 = 0.f, a10 = 0.f, a11 = 0.f;

        // dual-node main loop: 16 edges/node per iter, 2 u32 csr + 4 uint2
        // QVq loads in flight, 4 rcp per 8 gates.
        while (ndm >= 2) {
            const unsigned s0 = *(const unsigned*)(csr16 + b0 + 2 * eoff);
            const unsigned s1 = *(const unsigned*)(csr16 + b1 + 2 * eoff);
            const uint2 p0a = Qq2[(s0 & 0xFFFFu) * 8u + cp];
            const uint2 p0b = Qq2[(s0 >> 16) * 8u + cp];
            const uint2 p1a = Qq2[(s1 & 0xFFFFu) * 8u + cp];
            const uint2 p1b = Qq2[(s1 >> 16) * 8u + cp];
            GPAIR(ek00, p0a.x, p0b.x, a00);
            GPAIR(ek01, p0a.y, p0b.y, a01);
            GPAIR(ek10, p1a.x, p1b.x, a10);
            GPAIR(ek11, p1a.y, p1b.y, a11);
            b0 += 16; b1 += 16; ndm -= 2;
        }
        if (ndm) {   // one joint slot left (u16 per lane)
            const int s0 = csr16[b0 + eoff];
            const int s1 = csr16[b1 + eoff];
            const uint2 p0 = Qq2[(unsigned)(s0 * 8 + cp)];
            const uint2 p1 = Qq2[(unsigned)(s1 * 8 + cp)];
            GCOLS(ek00, ek01, p0, a00, a01);
            GCOLS(ek10, ek11, p1, a10, a11);
            b0 += 8; b1 += 8;
        }
        while (nd0 >= 2) {   // node-0 surplus, 16-edge steps
            const unsigned s0 = *(const unsigned*)(csr16 + b0 + 2 * eoff);
            const uint2 p0a = Qq2[(s0 & 0xFFFFu) * 8u + cp];
            const uint2 p0b = Qq2[(s0 >> 16) * 8u + cp];
            GPAIR(ek00, p0a.x, p0b.x, a00);
            GPAIR(ek01, p0a.y, p0b.y, a01);
            b0 += 16; nd0 -= 2;
        }
        if (nd0) {
            const int s0 = csr16[b0 + eoff];
            const uint2 p0 = Qq2[(unsigned)(s0 * 8 + cp)];
            GCOLS(ek00, ek01, p0, a00, a01);
        }
        while (nd1 >= 2) {   // node-1 surplus, 16-edge steps
            const unsigned s1 = *(const unsigned*)(csr16 + b1 + 2 * eoff);
            const uint2 p1a = Qq2[(s1 & 0xFFFFu) * 8u + cp];
            const uint2 p1b = Qq2[(s1 >> 16) * 8u + cp];
            GPAIR(ek10, p1a.x, p1b.x, a10);
            GPAIR(ek11, p1a.y, p1b.y, a11);
            b1 += 16; nd1 -= 2;
        }
        if (nd1) {
            const int s1 = csr16[b1 + eoff];
            const uint2 p1 = Qq2[(unsigned)(s1 * 8 + cp)];
            GCOLS(ek10, ek11, p1, a10, a11);
        }

        // combine edge slots: lanes cp, cp+8, ..., cp+56 share columns
        a00 += __shfl_xor(a00, 8);  a00 += __shfl_xor(a00, 16); a00 += __shfl_xor(a00, 32);
        a01 += __shfl_xor(a01, 8);  a01 += __shfl_xor(a01, 16); a01 += __shfl_xor(a01, 32);
        a10 += __shfl_xor(a10, 8);  a10 += __shfl_xor(a10, 16); a10 += __shfl_xor(a10, 32);
        a11 += __shfl_xor(a11, 8);  a11 += __shfl_xor(a11, 16); a11 += __shfl_xor(a11, 32);

        if (eoff == 0) {
            const float o00 = fmaxf(bf2f((unsigned short)(h0p & 0xFFFFu)) + a00, 0.f);
            const float o01 = fmaxf(bf2f((unsigned short)(h0p >> 16))     + a01, 0.f);
            const float o10 = fmaxf(bf2f((unsigned short)(h1p & 0xFFFFu)) + a10, 0.f);
            const float o11 = fmaxf(bf2f((unsigned short)(h1p >> 16))     + a11, 0.f);
            const unsigned short b00 = f2bf(o00), b01 = f2bf(o01);
            const unsigned short b10 = f2bf(o10), b11 = f2bf(o11);
            Hq32[ho0] = ((unsigned)b01 << 16) | b00;
            Hq32[ho1] = ((unsigned)b11 << 16) | b10;
            const float r00 = bf2f(b00), r01 = bf2f(b01);
            const float r10 = bf2f(b10), r11 = bf2f(b11);
            se  += r00 + r10;  s2e += r00 * r00 + r10 * r10;
            so  += r01 + r11;  s2o += r01 * r01 + r11 * r11;
        }
    }

    __shared__ float ls[64], ls2[64];   // 4 waves x 16 cols
    if (eoff == 0) {
        ls[wv * 16 + 2 * cp]      = se;  ls2[wv * 16 + 2 * cp]      = s2e;
        ls[wv * 16 + 2 * cp + 1]  = so;  ls2[wv * 16 + 2 * cp + 1]  = s2o;
    }
    __syncthreads();
    if (tid < 16) {
        const int rep = (j >> 3) & (SREP - 1);   // stats replica
        const float a = ls[tid] + ls[16 + tid] + ls[32 + tid] + ls[48 + tid];
        const float b = ls2[tid] + ls2[16 + tid] + ls2[32 + tid] + ls2[48 + tid];
        atomicAdd(&stats[rep * 128 + quarter * 16 + tid], a);
        atomicAdd(&stats[rep * 128 + 64 + quarter * 16 + tid], b);
    }
}

// ---------------------------------------------------------------------------
// Pooled segment-sum over quarter-major bf16 H (batch sorted). u32 loads;
// 128-thread blocks x 4 sub-chunks -> 196 blocks (was 98: underfilled the
// 256-CU chip for a 6.4 MB read).
// ---------------------------------------------------------------------------
__global__ __launch_bounds__(128) void pool_kernel(
    const unsigned short* __restrict__ Hq, const int* __restrict__ batch,
    float* __restrict__ psum, float* __restrict__ pcnt)
{
    const int sub = threadIdx.x >> 5;   // chunk 0..3
    const int c   = threadIdx.x & 31;   // col-pair id
    const int q   = c >> 3;             // quarter
    const int p   = c & 7;              // pair within quarter (cols 2p, 2p+1)
    const int r0 = (blockIdx.x * POOL_SUBS + sub) * POOL_ROWS;
    if (r0 >= NN) return;
    const int r1 = min(r0 + POOL_ROWS, NN);
    const unsigned* Hqq = (const unsigned*)(Hq + (size_t)q * NN * 16);
    const int col0 = q * 16 + 2 * p;

    int cur = batch[r0];
    float acc0 = 0.f, acc1 = 0.f, cnt = 0.f;
    for (int r = r0; r < r1; r++) {
        const int g = batch[r];
        if (g != cur) {
            atomicAdd(&psum[cur * DD + col0], acc0);
            atomicAdd(&psum[cur * DD + col0 + 1], acc1);
            if (c == 0) atomicAdd(&pcnt[cur], cnt);
            acc0 = 0.f; acc1 = 0.f; cnt = 0.f; cur = g;
        }
        const unsigned hv = Hqq[(size_t)r * 8 + p];
        acc0 += bf2f((unsigned short)(hv & 0xFFFFu));
        acc1 += bf2f((unsigned short)(hv >> 16));
        cnt += 1.f;
    }
    atomicAdd(&psum[cur * DD + col0], acc0);
    atomicAdd(&psum[cur * DD + col0 + 1], acc1);
    if (c == 0) atomicAdd(&pcnt[cur], cnt);
}

// ---------------------------------------------------------------------------
// Final head (R9-proven, ~2 us): one wave per graph; thread d owns column d;
// per-class wave shfl reduction; softmax in-register.
// ---------------------------------------------------------------------------
__global__ __launch_bounds__(64) void final_kernel(
    const float* __restrict__ psum, const float* __restrict__ pcnt,
    const float* __restrict__ stats,
    const float* __restrict__ gamma, const float* __restrict__ beta,
    const float* __restrict__ Wlin, const float* __restrict__ blin,
    float* __restrict__ out)
{
    const int g = blockIdx.x;        // graph
    const int d = threadIdx.x;       // column 0..63

    float s1 = 0.f, s2 = 0.f;
#pragma unroll
    for (int r = 0; r < SREP; r++) {
        s1 += stats[r * 128 + d];
        s2 += stats[r * 128 + 64 + d];
    }
    const float invN = 1.0f / (float)NN;
    const float mean = s1 * invN;
    const float var  = s2 * invN - mean * mean;
    const float inv  = rsqrtf(var + BN_EPS);
    const float a = inv * gamma[d];
    const float b = beta[d] - mean * a;
    const float invc = 1.0f / fmaxf(pcnt[g], 1.0f);
    const float pd = fmaf(psum[g * DD + d] * invc, a, b);

    float logits[NC];
#pragma unroll
    for (int c = 0; c < NC; c++) {
        float part = pd * Wlin[d * NC + c];
        part += __shfl_xor(part, 1);  part += __shfl_xor(part, 2);
        part += __shfl_xor(part, 4);  part += __shfl_xor(part, 8);
        part += __shfl_xor(part, 16); part += __shfl_xor(part, 32);
        logits[c] = part + blin[c];
    }
    float m = -1e30f;
#pragma unroll
    for (int c = 0; c < NC; c++) m = fmaxf(m, logits[c]);
    float sum = 0.f;
#pragma unroll
    for (int c = 0; c < NC; c++) {
        logits[c] = __expf(logits[c] - m);
        sum += logits[c];
    }
    const float invs = 1.f / sum;
    if (d < NC) {
        float mine = logits[0];
#pragma unroll
        for (int c = 1; c < NC; c++) mine = (d == c) ? logits[c] : mine;
        out[g * NC + d] = mine * invs;
    }
}

// ---------------------------------------------------------------------------
extern "C" void kernel_launch(void* const* d_in, const int* in_sizes, int n_in,
                              void* d_out, int out_size, void* d_ws, size_t ws_size,
                              hipStream_t stream)
{
    const float* X     = (const float*)d_in[0];
    const int*   ei    = (const int*)d_in[1];
    const int*   batch = (const int*)d_in[2];
    const float* Wk    = (const float*)d_in[3];
    const float* Wq    = (const float*)d_in[4];
    const float* Wv    = (const float*)d_in[5];
    const float* Ws    = (const float*)d_in[6];
    const float* bk    = (const float*)d_in[7];
    const float* bq    = (const float*)d_in[8];
    const float* bv    = (const float*)d_in[9];
    const float* bconv = (const float*)d_in[10];
    const float* gamma = (const float*)d_in[11];
    const float* beta  = (const float*)d_in[12];
    const float* Wlin  = (const float*)d_in[13];
    const float* blin  = (const float*)d_in[14];
    float* out = (float*)d_out;

    const size_t M  = (size_t)NN * DD;        // == 4 * NN * 16
    const size_t MQ = (size_t)4 * NNS * 16;   // QVq uints (padded stride)
    unsigned short* Kq  = (unsigned short*)d_ws;      // M bf16 (e^-k), quarter-major
    unsigned int*   QVq = (unsigned int*)(Kq + M);    // MQ packed (e^-q|v), stride NNS
    unsigned short* H0q = (unsigned short*)(QVq + MQ);// M bf16, quarter-major
    unsigned short* H1q = H0q + M;                    // M bf16
    // --- contiguous zero-init region ---
    int*   deg   = (int*)(H1q + M);                   // NN
    float* psum  = (float*)(deg + NN);                // NG*DD
    float* pcnt  = psum + (size_t)NG * DD;            // NG
    float* stats = pcnt + NG;                         // NL*SSTR (4-replica)
    // --- end zero region ---
    int* rowst  = (int*)(stats + NL * SSTR);          // NN+1
    int* cursor = rowst + NN + 1;                     // NN
    int* psums  = cursor + NN;                        // 256
    unsigned short* csr16 = (unsigned short*)(psums + 256);  // NE + 8*NN u16 (padded)
    bf16x8* whbuf = (bf16x8*)(csr16 + NE + 8 * NN);   // NL*2048 frags
    bf16x8* wlbuf = whbuf + NL * 2048;

    const size_t zero_bytes = (size_t)(NN + NG * DD + NG + NL * SSTR) * 4;
    hipMemsetAsync(deg, 0, zero_bytes, stream);

    // ---- fused deg histogram + W fragment prep + sentinel zeroing ----
    prep_kernel<<<DEG_BLOCKS + WPREP_BLOCKS, 256, 0, stream>>>(
        ei, deg, Wk, Wq, Wv, Ws, whbuf, wlbuf, QVq);

    // ---- scans over padded degrees (2 launches; offsets folded in) ----
    scan_partial_kernel<<<NCHUNK, 256, 0, stream>>>(deg, psums);
    scan_final_kernel<<<NCHUNK, 256, 0, stream>>>(deg, psums, rowst, cursor);

    // ---- fused layer-0 gemm + range-partitioned CSR fill + sentinel pad ----
    gfp_kernel<<<GEMM_BLOCKS + FILLP_BLOCKS + PAD_BLOCKS, 256, 0, stream>>>(
        X, whbuf, wlbuf, bk, bq, bv, bconv,
        Kq, QVq, H0q, ei, cursor, rowst, deg, csr16);

    // ---- layers ----
    gather_kernel<<<GATHER_BLOCKS, 256, 0, stream>>>(
        rowst, csr16, Kq, QVq, H0q, stats);
    const void* hin = (const void*)H0q;
    for (int l = 1; l < NL; l++) {
        unsigned short* hout = (l & 1) ? H1q : H0q;
        gemm4_mfma<<<GEMM_BLOCKS, 256, 0, stream>>>(
            hin, whbuf + l * 2048, wlbuf + l * 2048,
            bk + l * 64, bq + l * 64, bv + l * 64, bconv + l * 64,
            stats + (l - 1) * SSTR, gamma + (l - 1) * 64, beta + (l - 1) * 64,
            Kq, QVq, hout);
        gather_kernel<<<GATHER_BLOCKS, 256, 0, stream>>>(
            rowst, csr16, Kq, QVq, hout, stats + l * SSTR);
        hin = (const void*)hout;
    }

    pool_kernel<<<(NN + POOL_SUBS * POOL_ROWS - 1) / (POOL_SUBS * POOL_ROWS), 128, 0, stream>>>(
        (const unsigned short*)hin, batch, psum, pcnt);
    final_kernel<<<NG, 64, 0, stream>>>(
        psum, pcnt, stats + 4 * SSTR, gamma + 4 * 64, beta + 4 * 64, Wlin, blin, out);
}

// Round 11
// 447.568 us; speedup vs baseline: 1.2331x; 1.0141x over previous
//
#include <hip/hip_runtime.h>

#define NN 50000
#define NE 800000
#define DD 64
#define NL 5
#define NG 256
#define NC 10
#define BN_EPS 1e-5f
#define NCHUNK ((NN + 255) / 256)   // 196
#define GROWS 128                    // rows per gemm block (R4-proven)
#define GT (GROWS / 16)              // 16-row tiles per block
#define SAW 68                       // staged-A row stride (uints)
#define GEMM_BLOCKS ((NN + GROWS - 1) / GROWS)   // 391
#define NNS (NN + 8)                 // QVq per-quarter row stride (sentinel at row NN)
#define PADDEG(d) (((d) + 7) & ~7)   // csr segment padded to multiple of 8
#define DEG_BLOCKS ((NE + 255) / 256)        // 3125
#define WPREP_BLOCKS ((NL * 2048 + 255) / 256)  // 40
#define FCHK 2048                            // edges per fill chunk
#define FCHUNKS ((NE + FCHK - 1) / FCHK)     // 391
#define FILLP_BLOCKS (8 * FCHUNKS)           // 3128 (8 dst-ranges x chunks)
#define NRANGE (NN / 8)                      // 6250 nodes per dst-range
#define PAD_BLOCKS NCHUNK                    // 196
#define SREP 4                               // stats replicas (atomic contention /4)
#define SSTR (SREP * 128)                    // per-layer stats stride (512 floats)
#define POOL_ROWS 64
#define POOL_SUBS 4                          // 196 blocks
#define L2E 1.4426950408889634f              // log2(e)

typedef __attribute__((ext_vector_type(8))) short bf16x8;
typedef __attribute__((ext_vector_type(4))) float f32x4;

__device__ inline float bf2f(unsigned short u) {
    return __uint_as_float((unsigned)u << 16);
}
__device__ inline unsigned short f2bf(float x) {   // RNE
    unsigned u = __float_as_uint(x);
    u += 0x7FFFu + ((u >> 16) & 1u);
    return (unsigned short)(u >> 16);
}

// Pack two floats as bf16 (RNE) into one uint: low16 = a, high16 = b.
__device__ inline unsigned int pack_bf16x2(float a, float b) {
    unsigned int ua = __float_as_uint(a);
    unsigned int ub = __float_as_uint(b);
    ua += 0x7FFFu + ((ua >> 16) & 1u);
    ub += 0x7FFFu + ((ub >> 16) & 1u);
    return (ub & 0xFFFF0000u) | (ua >> 16);
}

// Split fp32 into bf16 hi (RTZ) + bf16 lo (residual). hi+lo ~ x to ~2^-17.
__device__ inline void split_bf16(float x, short& h, short& l) {
    const unsigned u  = __float_as_uint(x);
    const unsigned hb = u & 0xFFFF0000u;
    h = (short)(hb >> 16);
    const float lo = x - __uint_as_float(hb);
    l = (short)(__float_as_uint(lo) >> 16);
}

// packed (e^-q | v) accessors: low16 = e^-q, high16 = v.
__device__ inline float p_eq(unsigned p) { return __uint_as_float(p << 16); }
__device__ inline float p_v(unsigned p)  { return __uint_as_float(p & 0xFFFF0000u); }

// Two gates sharing one ek (batched reciprocal, 1 rcp for 2 gates):
// v1/t1 + v2/t2 = (v1*t2 + v2*t1) * rcp(t1*t2).  [numerics proven in R2]
#define GPAIR(ek, pa, pb, acc) { \
    const float t1_ = fmaf(ek, p_eq(pa), 1.f); \
    const float t2_ = fmaf(ek, p_eq(pb), 1.f); \
    const float R_  = __builtin_amdgcn_rcpf(t1_ * t2_); \
    acc = fmaf(fmaf(p_v(pb), t1_, p_v(pa) * t2_), R_, acc); }

// Two gates with different ek (one uint2's two cols): inverse recovery,
// R=rcp(t1*t2); 1/t1=R*t2; 1/t2=R*t1.  [numerics proven in R2]
#define GCOLS(ekx, eky, p, accx, accy) { \
    const float t1_ = fmaf(ekx, p_eq(p.x), 1.f); \
    const float t2_ = fmaf(eky, p_eq(p.y), 1.f); \
    const float R_  = __builtin_amdgcn_rcpf(t1_ * t2_); \
    accx = fmaf(p_v(p.x), R_ * t2_, accx); \
    accy = fmaf(p_v(p.y), R_ * t1_, accy); }

// ---------------------------------------------------------------------------
// Shared GEMM body (MFMA, inline prev-layer BN for bf16 path, QUARTER-MAJOR
// outputs): Kq stores e^-k; QVq packs (e^-q | v); Hq stores skip+bias.
// TRANSPOSED MFMA (operands swapped: mfma(W_frag, A_frag)) so each lane's
// 4 accumulator regs are 4 CONSECUTIVE COLUMNS of ONE node -> epilogue is
// 3 wide stores (ushort4/uint4/ushort4) instead of 12 narrow ones (4x fewer
// store instructions; ~9.6M -> 2.4M per gemm; stores were the gemm issue
// bottleneck). Memory layout of Kq/QVq/Hq is UNCHANGED (gather untouched).
// exp via raw v_exp_f32: e^-(acc+b) = 2^fma(acc,-log2e, -b*log2e).
// prevStats is 4-way replicated (SREP x 128) — summed here.
// F32=1: layer-0 path (fp32 X input, no BN fold).
// ---------------------------------------------------------------------------
template<int F32>
__device__ __forceinline__ void gemm_body(
    const void* __restrict__ HinV,
    const bf16x8* __restrict__ whbuf, const bf16x8* __restrict__ wlbuf,
    const float* __restrict__ bk, const float* __restrict__ bq,
    const float* __restrict__ bv, const float* __restrict__ bs,
    const float* __restrict__ prevStats,
    const float* __restrict__ prevGamma, const float* __restrict__ prevBeta,
    unsigned short* __restrict__ Kq, unsigned int* __restrict__ QVq,
    unsigned short* __restrict__ Hq, const int gb)
{
    __shared__ unsigned int sA[GROWS * SAW];   // packed split-bf16 A
    __shared__ float sAB[128];                 // a[64], b[64]
    const int tid = threadIdx.x;

    const int wave = tid >> 6;    // column tile == quarter
    const int lane = tid & 63;
    const int n15  = lane & 15;   // node-within-16 (transposed output)
    const int g    = lane >> 4;   // col-group: cols g*4..g*4+3 of the quarter
    const int col4 = wave * 16 + g * 4;

    // ---- hoisted W-fragment + bias loads (independent of staging) ----
    bf16x8 wh[4][2], wl[4][2];
    {
        const int base = wave * 64 + lane;
#pragma unroll
        for (int m = 0; m < 4; m++)
#pragma unroll
            for (int c = 0; c < 2; c++) {
                const int idx = m * 512 + c * 256 + base;
                wh[m][c] = whbuf[idx];
                wl[m][c] = wlbuf[idx];
            }
    }
    const float4 bk4 = *(const float4*)(bk + col4);
    const float4 bq4 = *(const float4*)(bq + col4);
    const float4 bv4 = *(const float4*)(bv + col4);
    const float4 bs4 = *(const float4*)(bs + col4);
    const float nbkA[4] = {-bk4.x * L2E, -bk4.y * L2E, -bk4.z * L2E, -bk4.w * L2E};
    const float nbqA[4] = {-bq4.x * L2E, -bq4.y * L2E, -bq4.z * L2E, -bq4.w * L2E};
    const float bvA[4]  = {bv4.x, bv4.y, bv4.z, bv4.w};
    const float bsA[4]  = {bs4.x, bs4.y, bs4.z, bs4.w};

    if (!F32) {
        if (tid < 64) {
            float s1 = 0.f, s2 = 0.f;
#pragma unroll
            for (int r = 0; r < SREP; r++) {
                s1 += prevStats[r * 128 + tid];
                s2 += prevStats[r * 128 + 64 + tid];
            }
            const float invN = 1.0f / (float)NN;
            const float mean = s1 * invN;
            const float var  = s2 * invN - mean * mean;
            const float inv  = rsqrtf(var + BN_EPS);
            const float a = inv * prevGamma[tid];
            sAB[tid]      = a;
            sAB[64 + tid] = prevBeta[tid] - mean * a;
        }
        __syncthreads();
    }

    const int row0 = gb * GROWS;
    if (F32) {
        const float* X = (const float*)HinV;
        for (int i = tid; i < GROWS * 16; i += 256) {
            const int row = i >> 4;
            const int k4  = (i & 15) * 4;
            float4 x = make_float4(0.f, 0.f, 0.f, 0.f);
            if (row0 + row < NN)
                x = *(const float4*)(X + (size_t)(row0 + row) * DD + k4);
            const float xs[4] = {x.x, x.y, x.z, x.w};
            unsigned int* dst = &sA[row * SAW + k4];
#pragma unroll
            for (int j = 0; j < 4; j++) {
                short hs, ls;
                split_bf16(xs[j], hs, ls);
                dst[j] = ((unsigned int)(unsigned short)hs << 16) | (unsigned short)ls;
            }
        }
    } else {
        const unsigned short* Hin = (const unsigned short*)HinV;
        for (int i = tid; i < GROWS * 8; i += 256) {
            const int row = i >> 3;
            const int cb  = (i & 7) * 8;   // col base: 0,8,..,56
            const int q   = cb >> 4;
            const int o16 = cb & 15;       // 0 or 8
            uint4 v = make_uint4(0u, 0u, 0u, 0u);
            if (row0 + row < NN)
                v = *(const uint4*)&Hin[((size_t)q * NN + row0 + row) * 16 + o16];
            const unsigned ws[4] = {v.x, v.y, v.z, v.w};
            unsigned int* dst = &sA[row * SAW + cb];
#pragma unroll
            for (int j = 0; j < 4; j++) {
                const float x0 = bf2f((unsigned short)(ws[j] & 0xFFFFu));
                const float x1 = bf2f((unsigned short)(ws[j] >> 16));
                const int c0 = cb + 2 * j, c1 = cb + 2 * j + 1;
                short hs, ls;
                split_bf16(fmaf(x0, sAB[c0], sAB[64 + c0]), hs, ls);
                dst[2 * j] = ((unsigned int)(unsigned short)hs << 16) | (unsigned short)ls;
                split_bf16(fmaf(x1, sAB[c1], sAB[64 + c1]), hs, ls);
                dst[2 * j + 1] = ((unsigned int)(unsigned short)hs << 16) | (unsigned short)ls;
            }
        }
    }

    __syncthreads();

#pragma unroll 1
    for (int t = 0; t < GT; t++) {
        const int rowbase = row0 + t * 16;
        if (rowbase >= NN) break;   // NN % 16 == 0

        bf16x8 ah[2], al[2];
#pragma unroll
        for (int c = 0; c < 2; c++) {
            const uint4 u0 = *(const uint4*)&sA[(t * 16 + n15) * SAW + g * 8 + 32 * c];
            const uint4 u1 = *(const uint4*)&sA[(t * 16 + n15) * SAW + g * 8 + 32 * c + 4];
            const unsigned int us[8] = {u0.x, u0.y, u0.z, u0.w, u1.x, u1.y, u1.z, u1.w};
            bf16x8 h, l;
#pragma unroll
            for (int j = 0; j < 8; j++) {
                h[j] = (short)(us[j] >> 16);
                l[j] = (short)(us[j] & 0xFFFFu);
            }
            ah[c] = h; al[c] = l;
        }

        f32x4 acc[4];
#pragma unroll
        for (int m = 0; m < 4; m++) acc[m] = (f32x4){0.f, 0.f, 0.f, 0.f};

        // swapped operands: D^T — result "row" dim = W cols, "col" dim = nodes
#pragma unroll
        for (int c = 0; c < 2; c++) {
#pragma unroll
            for (int m = 0; m < 4; m++) {
                acc[m] = __builtin_amdgcn_mfma_f32_16x16x32_bf16(wh[m][c], ah[c], acc[m], 0, 0, 0);
                acc[m] = __builtin_amdgcn_mfma_f32_16x16x32_bf16(wh[m][c], al[c], acc[m], 0, 0, 0);
                acc[m] = __builtin_amdgcn_mfma_f32_16x16x32_bf16(wl[m][c], ah[c], acc[m], 0, 0, 0);
            }
        }

        // lane holds cols col4..col4+3 of node rowbase+n15 -> 3 wide stores
        const size_t o  = ((size_t)wave * NN  + rowbase + n15) * 16 + g * 4;
        const size_t oq = ((size_t)wave * NNS + rowbase + n15) * 16 + g * 4;
        ushort4 kv, hv;
        uint4   qv;
#pragma unroll
        for (int r = 0; r < 4; r++) {
            const unsigned short kk =
                f2bf(__builtin_amdgcn_exp2f(fmaf(acc[0][r], -L2E, nbkA[r])));
            const unsigned int qq =
                pack_bf16x2(__builtin_amdgcn_exp2f(fmaf(acc[1][r], -L2E, nbqA[r])),
                            acc[2][r] + bvA[r]);
            const unsigned short hh = f2bf(acc[3][r] + bsA[r]);
            if (r == 0) { kv.x = kk; qv.x = qq; hv.x = hh; }
            if (r == 1) { kv.y = kk; qv.y = qq; hv.y = hh; }
            if (r == 2) { kv.z = kk; qv.z = qq; hv.z = hh; }
            if (r == 3) { kv.w = kk; qv.w = qq; hv.w = hh; }
        }
        *(ushort4*)(Kq + o)  = kv;
        *(uint4*)(QVq + oq)  = qv;
        *(ushort4*)(Hq + o)  = hv;
    }
}

// ---------------------------------------------------------------------------
// Fused prep: deg histogram (blocks 0..3124) + W-fragment split (blocks
// 3125..3164) + QVq sentinel-row zeroing. Independent work, one launch.
// ---------------------------------------------------------------------------
__global__ __launch_bounds__(256) void prep_kernel(
    const int* __restrict__ ei, int* __restrict__ deg,
    const float* __restrict__ Wk, const float* __restrict__ Wq,
    const float* __restrict__ Wv, const float* __restrict__ Ws,
    bf16x8* __restrict__ whbuf, bf16x8* __restrict__ wlbuf,
    unsigned int* __restrict__ QVq)
{
    const int bid = blockIdx.x;
    if (bid < DEG_BLOCKS) {
        const int e = bid * 256 + threadIdx.x;
        if (e < NE) atomicAdd(&deg[ei[NE + e]], 1);
        return;
    }
    if (bid == DEG_BLOCKS && threadIdx.x < 64) {
        const int q = threadIdx.x >> 4, c = threadIdx.x & 15;
        QVq[((size_t)q * NNS + NN) * 16 + c] = 0u;   // sentinel row: e^-q=0, v=0
    }
    const int t = (bid - DEG_BLOCKS) * 256 + threadIdx.x;
    if (t >= NL * 2048) return;
    const int lane = t & 63;
    const int w    = (t >> 6) & 3;
    const int c    = (t >> 8) & 1;
    const int m    = (t >> 9) & 3;
    const int l    = t >> 11;

    const float* Wm4[4] = {Wk, Wq, Wv, Ws};
    const float* W = Wm4[m] + l * 4096;
    const int col = w * 16 + (lane & 15);
    const int g   = lane >> 4;

    bf16x8 h, lo;
#pragma unroll
    for (int j = 0; j < 8; j++) {
        const int k = g * 8 + j + 32 * c;
        short hs, ls;
        split_bf16(W[k * DD + col], hs, ls);
        h[j] = hs; lo[j] = ls;
    }
    whbuf[t] = h;
    wlbuf[t] = lo;
}

// ---------------------------------------------------------------------------
// Scans over PADDED degrees (multiple of 8). Two launches; offsets folded
// into scan_final (wave-0 sums preceding psums, L2-hot).
// ---------------------------------------------------------------------------
__global__ __launch_bounds__(256) void scan_partial_kernel(
    const int* __restrict__ deg, int* __restrict__ psums)
{
    __shared__ int ls[256];
    const int i = blockIdx.x * 256 + threadIdx.x;
    ls[threadIdx.x] = (i < NN) ? PADDEG(deg[i]) : 0;
    __syncthreads();
    for (int off = 128; off > 0; off >>= 1) {
        if (threadIdx.x < off) ls[threadIdx.x] += ls[threadIdx.x + off];
        __syncthreads();
    }
    if (threadIdx.x == 0) psums[blockIdx.x] = ls[0];
}

__global__ __launch_bounds__(256) void scan_final_kernel(
    const int* __restrict__ deg, const int* __restrict__ psums,
    int* __restrict__ rowst, int* __restrict__ cursor)
{
    __shared__ int ls[256];
    __shared__ int sPref;
    const int i = blockIdx.x * 256 + threadIdx.x;
    const int x = (i < NN) ? PADDEG(deg[i]) : 0;
    ls[threadIdx.x] = x;
    __syncthreads();
    for (int off = 1; off < 256; off <<= 1) {
        int v = (threadIdx.x >= off) ? ls[threadIdx.x - off] : 0;
        __syncthreads();
        ls[threadIdx.x] += v;
        __syncthreads();
    }
    if (threadIdx.x < 64) {    // wave-0: block prefix over preceding psums
        int p = 0;
        for (int j = threadIdx.x; j < blockIdx.x; j += 64) p += psums[j];
        p += __shfl_xor(p, 1);  p += __shfl_xor(p, 2);  p += __shfl_xor(p, 4);
        p += __shfl_xor(p, 8);  p += __shfl_xor(p, 16); p += __shfl_xor(p, 32);
        if (threadIdx.x == 0) sPref = p;
    }
    __syncthreads();
    if (i < NN) {
        const int excl = sPref + ls[threadIdx.x] - x;
        rowst[i]  = excl;
        cursor[i] = excl;
    }
    if (blockIdx.x == NCHUNK - 1 && threadIdx.x == 255)
        rowst[NN] = sPref + ls[255];   // padded edge total
}

// ---------------------------------------------------------------------------
// Fused gemm0 + RANGE-PARTITIONED CSR fill + sentinel pad (R4-proven).
// ---------------------------------------------------------------------------
__global__ __launch_bounds__(256) void gfp_kernel(
    const float* __restrict__ X,
    const bf16x8* __restrict__ whbuf, const bf16x8* __restrict__ wlbuf,
    const float* __restrict__ bk, const float* __restrict__ bq,
    const float* __restrict__ bv, const float* __restrict__ bs,
    unsigned short* __restrict__ Kq, unsigned int* __restrict__ QVq,
    unsigned short* __restrict__ Hq,
    const int* __restrict__ ei, int* __restrict__ cursor,
    const int* __restrict__ rowst, const int* __restrict__ deg,
    unsigned short* __restrict__ csr16)
{
    const int bid = blockIdx.x;
    if (bid < GEMM_BLOCKS) {
        gemm_body<1>(X, whbuf, wlbuf, bk, bq, bv, bs,
                     nullptr, nullptr, nullptr, Kq, QVq, Hq, bid);
        return;
    }
    if (bid < GEMM_BLOCKS + FILLP_BLOCKS) {
        const int fid = bid - GEMM_BLOCKS;
        const int r   = bid & 7;            // dst-range == XCD (heuristic)
        const int o   = fid >> 3;           // edge chunk ordinal
        const int lo  = r * NRANGE;
        const int hi  = lo + NRANGE;
        const int e0  = o * FCHK;
        const int e1  = min(e0 + FCHK, NE);
        for (int e = e0 + threadIdx.x; e < e1; e += 256) {
            const int dst = ei[NE + e];
            if (dst >= lo && dst < hi) {
                const int src = ei[e];      // < 50000 < 65536 -> u16 exact
                csr16[atomicAdd(&cursor[dst], 1)] = (unsigned short)src;
            }
        }
        return;
    }
    const int n = (bid - GEMM_BLOCKS - FILLP_BLOCKS) * 256 + threadIdx.x;
    if (n >= NN) return;
    const int end = rowst[n + 1];
    for (int i = rowst[n] + deg[n]; i < end; i++) csr16[i] = (unsigned short)NN;
}

// ---------------------------------------------------------------------------
// gemm for layers 1..4 (bf16 input, prev-layer BN folded from replicated
// stats).
// ---------------------------------------------------------------------------
__global__ __launch_bounds__(256) void gemm4_mfma(
    const void* __restrict__ HinV,
    const bf16x8* __restrict__ whbuf, const bf16x8* __restrict__ wlbuf,
    const float* __restrict__ bk, const float* __restrict__ bq,
    const float* __restrict__ bv, const float* __restrict__ bs,
    const float* __restrict__ prevStats,
    const float* __restrict__ prevGamma, const float* __restrict__ prevBeta,
    unsigned short* __restrict__ Kq, unsigned int* __restrict__ QVq,
    unsigned short* __restrict__ Hq)
{
    gemm_body<0>(HinV, whbuf, wlbuf, bk, bq, bv, bs,
                 prevStats, prevGamma, prevBeta, Kq, QVq, Hq, blockIdx.x);
}

// ---------------------------------------------------------------------------
// Column-quarter XCD-partitioned gather — R4 body + replicated stats
// atomics (R8/R9-proven, ~45 us). FROZEN: three scheduling grafts (R2 full
// restructure, R5 readfirstlane, R6 csr prefetch) all regressed; only work
// removal has ever helped this kernel.
// ---------------------------------------------------------------------------
#define GATHER_BLOCKS (8 * 782)   // 6256
__global__ __launch_bounds__(256) void gather_kernel(
    const int* __restrict__ rowst, const unsigned short* __restrict__ csr16,
    const unsigned short* __restrict__ Kq, const unsigned int* __restrict__ QVq,
    unsigned short* Hq, float* __restrict__ stats)
{
    const int tid  = threadIdx.x;
    const int wv   = tid >> 6;
    const int lane = tid & 63;
    const int eoff = lane >> 3;     // edge slot 0..7
    const int cp   = lane & 7;      // column pair (cols 2cp, 2cp+1)

    const int j       = blockIdx.x;
    const int xcd     = j & 7;
    const int quarter = xcd >> 1;
    const int half    = xcd & 1;
    const int nodebase = ((j >> 3) * 2 + half) * 32 + wv * 8;

    const unsigned* Kq32 = (const unsigned*)(Kq + (size_t)quarter * NN * 16);
    const uint2*    Qq2  = (const uint2*)(QVq + (size_t)quarter * NNS * 16);
    unsigned*       Hq32 = (unsigned*)(Hq + (size_t)quarter * NN * 16);

    float se = 0.f, s2e = 0.f, so = 0.f, s2o = 0.f;   // stats cols 2cp / 2cp+1

    int e00 = rowst[min(nodebase, NN)];   // carried: e00(t+1) = e11(t)

    for (int t = 0; t < 4; t++) {
        const int n0 = nodebase + 2 * t;   // even; n1 = n0+1 < NN when n0 < NN
        if (n0 >= NN) break;
        const int n1 = n0 + 1;
        const unsigned ho0 = (unsigned)(n0 * 8 + cp);
        const unsigned ho1 = (unsigned)(n1 * 8 + cp);
        unsigned h0p = 0u, h1p = 0u;
        if (eoff == 0) {                   // exec-masked prefetch of skip term
            h0p = Hq32[ho0];
            h1p = Hq32[ho1];
        }
        const unsigned k0p = Kq32[ho0];    // packed e^-k
        const unsigned k1p = Kq32[ho1];
        const float ek00 = bf2f((unsigned short)(k0p & 0xFFFFu));
        const float ek01 = bf2f((unsigned short)(k0p >> 16));
        const float ek10 = bf2f((unsigned short)(k1p & 0xFFFFu));
        const float ek11 = bf2f((unsigned short)(k1p >> 16));
        const int e01 = rowst[n1], e11 = rowst[n1 + 1];
        int nd0 = (e01 - e00) >> 3;        // padded slot counts
        int nd1 = (e11 - e01) >> 3;
        int ndm = min(nd0, nd1);
        nd0 -= ndm; nd1 -= ndm;
        int b0 = e00, b1 = e01;            // base edge indices (even)
        e00 = e11;                         // carry for next t
        float a00 = 0.f, a01 = 0.f, a10 = 0.f, a11 = 0.f;

        // dual-node main loop: 16 edges/node per iter, 2 u32 csr + 4 uint2
        // QVq loads in flight, 4 rcp per 8 gates.
        while (ndm >= 2) {
            const unsigned s0 = *(const unsigned*)(csr16 + b0 + 2 * eoff);
            const unsigned s1 = *(const unsigned*)(csr16 + b1 + 2 * eoff);
            const uint2 p0a = Qq2[(s0 & 0xFFFFu) * 8u + cp];
            const uint2 p0b = Qq2[(s0 >> 16) * 8u + cp];
            const uint2 p1a = Qq2[(s1 & 0xFFFFu) * 8u + cp];
            const uint2 p1b = Qq2[(s1 >> 16) * 8u + cp];
            GPAIR(ek00, p0a.x, p0b.x, a00);
            GPAIR(ek01, p0a.y, p0b.y, a01);
            GPAIR(ek10, p1a.x, p1b.x, a10);
            GPAIR(ek11, p1a.y, p1b.y, a11);
            b0 += 16; b1 += 16; ndm -= 2;
        }
        if (ndm) {   // one joint slot left (u16 per lane)
            const int s0 = csr16[b0 + eoff];
            const int s1 = csr16[b1 + eoff];
            const uint2 p0 = Qq2[(unsigned)(s0 * 8 + cp)];
            const uint2 p1 = Qq2[(unsigned)(s1 * 8 + cp)];
            GCOLS(ek00, ek01, p0, a00, a01);
            GCOLS(ek10, ek11, p1, a10, a11);
            b0 += 8; b1 += 8;
        }
        while (nd0 >= 2) {   // node-0 surplus, 16-edge steps
            const unsigned s0 = *(const unsigned*)(csr16 + b0 + 2 * eoff);
            const uint2 p0a = Qq2[(s0 & 0xFFFFu) * 8u + cp];
            const uint2 p0b = Qq2[(s0 >> 16) * 8u + cp];
            GPAIR(ek00, p0a.x, p0b.x, a00);
            GPAIR(ek01, p0a.y, p0b.y, a01);
            b0 += 16; nd0 -= 2;
        }
        if (nd0) {
            const int s0 = csr16[b0 + eoff];
            const uint2 p0 = Qq2[(unsigned)(s0 * 8 + cp)];
            GCOLS(ek00, ek01, p0, a00, a01);
        }
        while (nd1 >= 2) {   // node-1 surplus, 16-edge steps
            const unsigned s1 = *(const unsigned*)(csr16 + b1 + 2 * eoff);
            const uint2 p1a = Qq2[(s1 & 0xFFFFu) * 8u + cp];
            const uint2 p1b = Qq2[(s1 >> 16) * 8u + cp];
            GPAIR(ek10, p1a.x, p1b.x, a10);
            GPAIR(ek11, p1a.y, p1b.y, a11);
            b1 += 16; nd1 -= 2;
        }
        if (nd1) {
            const int s1 = csr16[b1 + eoff];
            const uint2 p1 = Qq2[(unsigned)(s1 * 8 + cp)];
            GCOLS(ek10, ek11, p1, a10, a11);
        }

        // combine edge slots: lanes cp, cp+8, ..., cp+56 share columns
        a00 += __shfl_xor(a00, 8);  a00 += __shfl_xor(a00, 16); a00 += __shfl_xor(a00, 32);
        a01 += __shfl_xor(a01, 8);  a01 += __shfl_xor(a01, 16); a01 += __shfl_xor(a01, 32);
        a10 += __shfl_xor(a10, 8);  a10 += __shfl_xor(a10, 16); a10 += __shfl_xor(a10, 32);
        a11 += __shfl_xor(a11, 8);  a11 += __shfl_xor(a11, 16); a11 += __shfl_xor(a11, 32);

        if (eoff == 0) {
            const float o00 = fmaxf(bf2f((unsigned short)(h0p & 0xFFFFu)) + a00, 0.f);
            const float o01 = fmaxf(bf2f((unsigned short)(h0p >> 16))     + a01, 0.f);
            const float o10 = fmaxf(bf2f((unsigned short)(h1p & 0xFFFFu)) + a10, 0.f);
            const float o11 = fmaxf(bf2f((unsigned short)(h1p >> 16))     + a11, 0.f);
            const unsigned short b00 = f2bf(o00), b01 = f2bf(o01);
            const unsigned short b10 = f2bf(o10), b11 = f2bf(o11);
            Hq32[ho0] = ((unsigned)b01 << 16) | b00;
            Hq32[ho1] = ((unsigned)b11 << 16) | b10;
            const float r00 = bf2f(b00), r01 = bf2f(b01);
            const float r10 = bf2f(b10), r11 = bf2f(b11);
            se  += r00 + r10;  s2e += r00 * r00 + r10 * r10;
            so  += r01 + r11;  s2o += r01 * r01 + r11 * r11;
        }
    }

    __shared__ float ls[64], ls2[64];   // 4 waves x 16 cols
    if (eoff == 0) {
        ls[wv * 16 + 2 * cp]      = se;  ls2[wv * 16 + 2 * cp]      = s2e;
        ls[wv * 16 + 2 * cp + 1]  = so;  ls2[wv * 16 + 2 * cp + 1]  = s2o;
    }
    __syncthreads();
    if (tid < 16) {
        const int rep = (j >> 3) & (SREP - 1);   // stats replica
        const float a = ls[tid] + ls[16 + tid] + ls[32 + tid] + ls[48 + tid];
        const float b = ls2[tid] + ls2[16 + tid] + ls2[32 + tid] + ls2[48 + tid];
        atomicAdd(&stats[rep * 128 + quarter * 16 + tid], a);
        atomicAdd(&stats[rep * 128 + 64 + quarter * 16 + tid], b);
    }
}

// ---------------------------------------------------------------------------
// Pooled segment-sum over quarter-major bf16 H (batch sorted). u32 loads;
// 128-thread blocks x 4 sub-chunks -> 196 blocks.
// ---------------------------------------------------------------------------
__global__ __launch_bounds__(128) void pool_kernel(
    const unsigned short* __restrict__ Hq, const int* __restrict__ batch,
    float* __restrict__ psum, float* __restrict__ pcnt)
{
    const int sub = threadIdx.x >> 5;   // chunk 0..3
    const int c   = threadIdx.x & 31;   // col-pair id
    const int q   = c >> 3;             // quarter
    const int p   = c & 7;              // pair within quarter (cols 2p, 2p+1)
    const int r0 = (blockIdx.x * POOL_SUBS + sub) * POOL_ROWS;
    if (r0 >= NN) return;
    const int r1 = min(r0 + POOL_ROWS, NN);
    const unsigned* Hqq = (const unsigned*)(Hq + (size_t)q * NN * 16);
    const int col0 = q * 16 + 2 * p;

    int cur = batch[r0];
    float acc0 = 0.f, acc1 = 0.f, cnt = 0.f;
    for (int r = r0; r < r1; r++) {
        const int g = batch[r];
        if (g != cur) {
            atomicAdd(&psum[cur * DD + col0], acc0);
            atomicAdd(&psum[cur * DD + col0 + 1], acc1);
            if (c == 0) atomicAdd(&pcnt[cur], cnt);
            acc0 = 0.f; acc1 = 0.f; cnt = 0.f; cur = g;
        }
        const unsigned hv = Hqq[(size_t)r * 8 + p];
        acc0 += bf2f((unsigned short)(hv & 0xFFFFu));
        acc1 += bf2f((unsigned short)(hv >> 16));
        cnt += 1.f;
    }
    atomicAdd(&psum[cur * DD + col0], acc0);
    atomicAdd(&psum[cur * DD + col0 + 1], acc1);
    if (c == 0) atomicAdd(&pcnt[cur], cnt);
}

// ---------------------------------------------------------------------------
// Final head (R9-proven, ~2 us): one wave per graph; thread d owns column d;
// per-class wave shfl reduction; softmax in-register.
// ---------------------------------------------------------------------------
__global__ __launch_bounds__(64) void final_kernel(
    const float* __restrict__ psum, const float* __restrict__ pcnt,
    const float* __restrict__ stats,
    const float* __restrict__ gamma, const float* __restrict__ beta,
    const float* __restrict__ Wlin, const float* __restrict__ blin,
    float* __restrict__ out)
{
    const int g = blockIdx.x;        // graph
    const int d = threadIdx.x;       // column 0..63

    float s1 = 0.f, s2 = 0.f;
#pragma unroll
    for (int r = 0; r < SREP; r++) {
        s1 += stats[r * 128 + d];
        s2 += stats[r * 128 + 64 + d];
    }
    const float invN = 1.0f / (float)NN;
    const float mean = s1 * invN;
    const float var  = s2 * invN - mean * mean;
    const float inv  = rsqrtf(var + BN_EPS);
    const float a = inv * gamma[d];
    const float b = beta[d] - mean * a;
    const float invc = 1.0f / fmaxf(pcnt[g], 1.0f);
    const float pd = fmaf(psum[g * DD + d] * invc, a, b);

    float logits[NC];
#pragma unroll
    for (int c = 0; c < NC; c++) {
        float part = pd * Wlin[d * NC + c];
        part += __shfl_xor(part, 1);  part += __shfl_xor(part, 2);
        part += __shfl_xor(part, 4);  part += __shfl_xor(part, 8);
        part += __shfl_xor(part, 16); part += __shfl_xor(part, 32);
        logits[c] = part + blin[c];
    }
    float m = -1e30f;
#pragma unroll
    for (int c = 0; c < NC; c++) m = fmaxf(m, logits[c]);
    float sum = 0.f;
#pragma unroll
    for (int c = 0; c < NC; c++) {
        logits[c] = __expf(logits[c] - m);
        sum += logits[c];
    }
    const float invs = 1.f / sum;
    if (d < NC) {
        float mine = logits[0];
#pragma unroll
        for (int c = 1; c < NC; c++) mine = (d == c) ? logits[c] : mine;
        out[g * NC + d] = mine * invs;
    }
}

// ---------------------------------------------------------------------------
extern "C" void kernel_launch(void* const* d_in, const int* in_sizes, int n_in,
                              void* d_out, int out_size, void* d_ws, size_t ws_size,
                              hipStream_t stream)
{
    const float* X     = (const float*)d_in[0];
    const int*   ei    = (const int*)d_in[1];
    const int*   batch = (const int*)d_in[2];
    const float* Wk    = (const float*)d_in[3];
    const float* Wq    = (const float*)d_in[4];
    const float* Wv    = (const float*)d_in[5];
    const float* Ws    = (const float*)d_in[6];
    const float* bk    = (const float*)d_in[7];
    const float* bq    = (const float*)d_in[8];
    const float* bv    = (const float*)d_in[9];
    const float* bconv = (const float*)d_in[10];
    const float* gamma = (const float*)d_in[11];
    const float* beta  = (const float*)d_in[12];
    const float* Wlin  = (const float*)d_in[13];
    const float* blin  = (const float*)d_in[14];
    float* out = (float*)d_out;

    const size_t M  = (size_t)NN * DD;        // == 4 * NN * 16
    const size_t MQ = (size_t)4 * NNS * 16;   // QVq uints (padded stride)
    unsigned short* Kq  = (unsigned short*)d_ws;      // M bf16 (e^-k), quarter-major
    unsigned int*   QVq = (unsigned int*)(Kq + M);    // MQ packed (e^-q|v), stride NNS
    unsigned short* H0q = (unsigned short*)(QVq + MQ);// M bf16, quarter-major
    unsigned short* H1q = H0q + M;                    // M bf16
    // --- contiguous zero-init region ---
    int*   deg   = (int*)(H1q + M);                   // NN
    float* psum  = (float*)(deg + NN);                // NG*DD
    float* pcnt  = psum + (size_t)NG * DD;            // NG
    float* stats = pcnt + NG;                         // NL*SSTR (4-replica)
    // --- end zero region ---
    int* rowst  = (int*)(stats + NL * SSTR);          // NN+1
    int* cursor = rowst + NN + 1;                     // NN
    int* psums  = cursor + NN;                        // 256
    unsigned short* csr16 = (unsigned short*)(psums + 256);  // NE + 8*NN u16 (padded)
    bf16x8* whbuf = (bf16x8*)(csr16 + NE + 8 * NN);   // NL*2048 frags
    bf16x8* wlbuf = whbuf + NL * 2048;

    const size_t zero_bytes = (size_t)(NN + NG * DD + NG + NL * SSTR) * 4;
    hipMemsetAsync(deg, 0, zero_bytes, stream);

    // ---- fused deg histogram + W fragment prep + sentinel zeroing ----
    prep_kernel<<<DEG_BLOCKS + WPREP_BLOCKS, 256, 0, stream>>>(
        ei, deg, Wk, Wq, Wv, Ws, whbuf, wlbuf, QVq);

    // ---- scans over padded degrees (2 launches; offsets folded in) ----
    scan_partial_kernel<<<NCHUNK, 256, 0, stream>>>(deg, psums);
    scan_final_kernel<<<NCHUNK, 256, 0, stream>>>(deg, psums, rowst, cursor);

    // ---- fused layer-0 gemm + range-partitioned CSR fill + sentinel pad ----
    gfp_kernel<<<GEMM_BLOCKS + FILLP_BLOCKS + PAD_BLOCKS, 256, 0, stream>>>(
        X, whbuf, wlbuf, bk, bq, bv, bconv,
        Kq, QVq, H0q, ei, cursor, rowst, deg, csr16);

    // ---- layers ----
    gather_kernel<<<GATHER_BLOCKS, 256, 0, stream>>>(
        rowst, csr16, Kq, QVq, H0q, stats);
    const void* hin = (const void*)H0q;
    for (int l = 1; l < NL; l++) {
        unsigned short* hout = (l & 1) ? H1q : H0q;
        gemm4_mfma<<<GEMM_BLOCKS, 256, 0, stream>>>(
            hin, whbuf + l * 2048, wlbuf + l * 2048,
            bk + l * 64, bq + l * 64, bv + l * 64, bconv + l * 64,
            stats + (l - 1) * SSTR, gamma + (l - 1) * 64, beta + (l - 1) * 64,
            Kq, QVq, hout);
        gather_kernel<<<GATHER_BLOCKS, 256, 0, stream>>>(
            rowst, csr16, Kq, QVq, hout, stats + l * SSTR);
        hin = (const void*)hout;
    }

    pool_kernel<<<(NN + POOL_SUBS * POOL_ROWS - 1) / (POOL_SUBS * POOL_ROWS), 128, 0, stream>>>(
        (const unsigned short*)hin, batch, psum, pcnt);
    final_kernel<<<NG, 64, 0, stream>>>(
        psum, pcnt, stats + 4 * SSTR, gamma + 4 * 64, beta + 4 * 64, Wlin, blin, out);
}